// Round 1
// baseline (1737.249 us; speedup 1.0000x reference)
//
#include <hip/hip_runtime.h>
#include <math.h>

// ---------------------------------------------------------------------------
// TransformerNet: 4x TransformerConv (heads=1) + ELU, GlobalAttention pool,
// final linear.  fp32 throughout (threshold allows bf16-level error; we keep
// fp32 this round for correctness).
// ---------------------------------------------------------------------------

#define BM 64
#define BN 64
#define BK 16

// C[M,N] = A[M,K] @ W[K,N] + bias[N]
__global__ __launch_bounds__(256) void gemm_bias_kernel(
    const float* __restrict__ A, const float* __restrict__ W,
    const float* __restrict__ bias, float* __restrict__ C,
    int M, int K, int N) {
  __shared__ float As[BK][BM + 1];
  __shared__ float Ws[BK][BN];
  const int tid = threadIdx.x;
  const int bx = blockIdx.x, by = blockIdx.y;
  const int tcol = tid & 15;   // N direction (0..15)
  const int trow = tid >> 4;   // M direction (0..15)

  // A-tile load mapping: 64x16 tile, each thread loads 4 consecutive k's
  const int a_r = tid >> 2;          // 0..63 row within tile
  const int a_c = (tid & 3) * 4;     // 0,4,8,12 col (k) within tile
  const int arow = by * BM + a_r;
  // W-tile load mapping: 16x64 tile, each thread loads 4 consecutive n's
  const int w_r = tid >> 4;          // 0..15 (k within tile)
  const int w_c = (tid & 15) * 4;    // 0..60
  const int wcol = bx * BN + w_c;

  float acc[4][4];
#pragma unroll
  for (int i = 0; i < 4; ++i)
#pragma unroll
    for (int j = 0; j < 4; ++j) acc[i][j] = 0.f;

  for (int k0 = 0; k0 < K; k0 += BK) {
    float4 av = make_float4(0.f, 0.f, 0.f, 0.f);
    if (arow < M) av = *(const float4*)(A + (size_t)arow * K + k0 + a_c);
    As[a_c + 0][a_r] = av.x;
    As[a_c + 1][a_r] = av.y;
    As[a_c + 2][a_r] = av.z;
    As[a_c + 3][a_r] = av.w;

    float4 wv = make_float4(0.f, 0.f, 0.f, 0.f);
    if (wcol < N) wv = *(const float4*)(W + (size_t)(k0 + w_r) * N + wcol);
    *(float4*)&Ws[w_r][w_c] = wv;

    __syncthreads();
#pragma unroll
    for (int kk = 0; kk < BK; ++kk) {
      float a[4], b[4];
#pragma unroll
      for (int i = 0; i < 4; ++i) a[i] = As[kk][trow * 4 + i];
#pragma unroll
      for (int j = 0; j < 4; ++j) b[j] = Ws[kk][tcol * 4 + j];
#pragma unroll
      for (int i = 0; i < 4; ++i)
#pragma unroll
        for (int j = 0; j < 4; ++j) acc[i][j] += a[i] * b[j];
    }
    __syncthreads();
  }

  const int row0 = by * BM + trow * 4;
  const int col0 = bx * BN + tcol * 4;
#pragma unroll
  for (int i = 0; i < 4; ++i) {
    int r = row0 + i;
    if (r >= M) break;
#pragma unroll
    for (int j = 0; j < 4; ++j) {
      int c = col0 + j;
      if (c < N) C[(size_t)r * N + c] = acc[i][j] + bias[c];
    }
  }
}

// ---------------- CSR build ----------------
__global__ void hist_kernel(const int* __restrict__ dst, int* __restrict__ deg, int E) {
  int e = blockIdx.x * blockDim.x + threadIdx.x;
  if (e < E) atomicAdd(&deg[dst[e]], 1);
}

__global__ __launch_bounds__(1024) void scan_kernel(const int* __restrict__ deg,
                                                    int* __restrict__ offs, int N) {
  __shared__ int sums[1024];
  const int tid = threadIdx.x;
  const int chunk = (N + 1023) / 1024;
  const int start = tid * chunk;
  int s = 0;
  for (int i = 0; i < chunk; ++i) {
    int idx = start + i;
    if (idx < N) s += deg[idx];
  }
  sums[tid] = s;
  __syncthreads();
  for (int off = 1; off < 1024; off <<= 1) {
    int t = (tid >= off) ? sums[tid - off] : 0;
    __syncthreads();
    sums[tid] += t;
    __syncthreads();
  }
  int run = (tid == 0) ? 0 : sums[tid - 1];
  for (int i = 0; i < chunk; ++i) {
    int idx = start + i;
    if (idx < N) {
      offs[idx] = run;
      run += deg[idx];
    }
  }
  if (tid == 1023) offs[N] = sums[1023];
}

__global__ void scatter_kernel(const int* __restrict__ src, const int* __restrict__ dst,
                               const int* __restrict__ offs, int* __restrict__ cursor,
                               int* __restrict__ csr_src, int E) {
  int e = blockIdx.x * blockDim.x + threadIdx.x;
  if (e >= E) return;
  int d = dst[e];
  int pos = offs[d] + atomicAdd(&cursor[d], 1);
  csr_src[pos] = src[e];
}

// ---------------- per-node attention aggregate (one wave per dst node) -----
// h_out already contains skip = h_in @ Ws + bs; this kernel does
// h_out = elu(softmax-agg + skip) in place.
__global__ __launch_bounds__(256) void attn_kernel(
    const float* __restrict__ q, const float* __restrict__ k,
    const float* __restrict__ v, const int* __restrict__ csr_src,
    const int* __restrict__ offs, float* __restrict__ h_out, int N, int d) {
  const int wid = (blockIdx.x * 256 + threadIdx.x) >> 6;
  const int lane = threadIdx.x & 63;
  if (wid >= N) return;
  const int begin = offs[wid];
  const int end = offs[wid + 1];
  const float scale = 1.0f / sqrtf((float)d);
  const int nj = (d + 63) >> 6;

  const float* qn = q + (size_t)wid * d;
  float qreg[8];
#pragma unroll
  for (int j = 0; j < 8; ++j) qreg[j] = 0.f;
  for (int j = 0; j < nj; ++j) {
    int i = lane + (j << 6);
    if (i < d) qreg[j] = qn[i];
  }

  // pass 1: max logit
  float m = -INFINITY;
  for (int pos = begin; pos < end; ++pos) {
    int s = csr_src[pos];
    const float* ks = k + (size_t)s * d;
    float p = 0.f;
    for (int j = 0; j < nj; ++j) {
      int i = lane + (j << 6);
      if (i < d) p += qreg[j] * ks[i];
    }
#pragma unroll
    for (int off = 32; off; off >>= 1) p += __shfl_xor(p, off);
    m = fmaxf(m, p * scale);
  }

  // pass 2: exp-sum + weighted v aggregate (recompute dot: deterministic,
  // avoids cross-lane-through-memory hazards)
  float ssum = 0.f;
  float acc[8];
#pragma unroll
  for (int j = 0; j < 8; ++j) acc[j] = 0.f;
  for (int pos = begin; pos < end; ++pos) {
    int s = csr_src[pos];
    const float* ks = k + (size_t)s * d;
    const float* vs = v + (size_t)s * d;
    float p = 0.f;
    for (int j = 0; j < nj; ++j) {
      int i = lane + (j << 6);
      if (i < d) p += qreg[j] * ks[i];
    }
#pragma unroll
    for (int off = 32; off; off >>= 1) p += __shfl_xor(p, off);
    float wgt = expf(p * scale - m);
    ssum += wgt;
    for (int j = 0; j < nj; ++j) {
      int i = lane + (j << 6);
      if (i < d) acc[j] += wgt * vs[i];
    }
  }

  float inv = (end > begin) ? (1.0f / ssum) : 0.f;
  float* on = h_out + (size_t)wid * d;
  for (int j = 0; j < nj; ++j) {
    int i = lane + (j << 6);
    if (i < d) {
      float val = acc[j] * inv + on[i];
      on[i] = (val > 0.f) ? val : expm1f(val);
    }
  }
}

// ---------------- pooling ----------------
__device__ inline void atomicMaxFloat(float* addr, float val) {
  unsigned int* ua = (unsigned int*)addr;
  unsigned int old = *ua;
  while (true) {
    float f = __uint_as_float(old);
    if (f >= val) break;
    unsigned int assumed = old;
    old = atomicCAS(ua, assumed, __float_as_uint(val));
    if (old == assumed) break;
  }
}

__global__ void init_pool_kernel(float* gmax, float* gsum, float* pooled) {
  int t = threadIdx.x;  // 512
  if (t < 16) {
    gmax[t] = -INFINITY;
    gsum[t] = 0.f;
  }
  if (t < 512) pooled[t] = 0.f;
}

__global__ void gate_kernel(const float* __restrict__ h, const float* __restrict__ Wg,
                            const float* __restrict__ bg, const int* __restrict__ batch,
                            float* __restrict__ gate, float* __restrict__ gmax, int N) {
  int n = blockIdx.x * blockDim.x + threadIdx.x;
  if (n >= N) return;
  float g = bg[0];
  const float* hn = h + (size_t)n * 32;
#pragma unroll
  for (int i = 0; i < 32; ++i) g += hn[i] * Wg[i];
  gate[n] = g;
  atomicMaxFloat(&gmax[batch[n]], g);
}

__global__ void expsum_kernel(const float* __restrict__ gate, const int* __restrict__ batch,
                              const float* __restrict__ gmax, float* __restrict__ en,
                              float* __restrict__ gsum, int N) {
  int n = blockIdx.x * blockDim.x + threadIdx.x;
  if (n >= N) return;
  int b = batch[n];
  float e = expf(gate[n] - gmax[b]);
  en[n] = e;
  atomicAdd(&gsum[b], e);
}

__global__ void poolacc_kernel(const float* __restrict__ h, const int* __restrict__ batch,
                               const float* __restrict__ en, const float* __restrict__ gsum,
                               float* __restrict__ pooled, int N) {
  int idx = blockIdx.x * blockDim.x + threadIdx.x;
  if (idx >= N * 32) return;
  int n = idx >> 5;
  int i = idx & 31;
  int b = batch[n];
  float a = en[n] / gsum[b];
  atomicAdd(&pooled[b * 32 + i], a * h[(size_t)n * 32 + i]);
}

__global__ void final_kernel(const float* __restrict__ pooled, const float* __restrict__ Wf,
                             const float* __restrict__ bf, float* __restrict__ out) {
  int t = threadIdx.x;
  if (t >= 16 * 9) return;
  int g = t / 9;
  int j = t % 9;
  float s = bf[j];
#pragma unroll
  for (int kk = 0; kk < 32; ++kk) s += pooled[g * 32 + kk] * Wf[kk * 9 + j];
  out[g * 9 + j] = s;
}

// ---------------------------------------------------------------------------
extern "C" void kernel_launch(void* const* d_in, const int* in_sizes, int n_in,
                              void* d_out, int out_size, void* d_ws, size_t ws_size,
                              hipStream_t stream) {
  const int IN_FEAT = 128;
  const int N = in_sizes[2];       // 10000 nodes (batch array length)
  const int E = in_sizes[1] / 2;   // 160000 edges
  (void)IN_FEAT;

  const float* x = (const float*)d_in[0];
  const int* ei = (const int*)d_in[1];
  const int* batch = (const int*)d_in[2];
  const int* src = ei;
  const int* dst = ei + E;
  const float* Wg = (const float*)d_in[35];
  const float* bg = (const float*)d_in[36];
  const float* Wf = (const float*)d_in[37];
  const float* bf = (const float*)d_in[38];
  float* out = (float*)d_out;

  // workspace carve-up (256-B aligned)
  char* p = (char*)d_ws;
  auto carve = [&](size_t bytes) -> char* {
    char* r = p;
    p += (bytes + 255) & ~(size_t)255;
    return r;
  };
  int* deg = (int*)carve((size_t)N * 4);
  int* offs = (int*)carve((size_t)(N + 1) * 4);
  int* cursor = (int*)carve((size_t)N * 4);
  int* csr_src = (int*)carve((size_t)E * 4);
  float* qb = (float*)carve((size_t)N * 512 * 4);
  float* kb = (float*)carve((size_t)N * 512 * 4);
  float* vb = (float*)carve((size_t)N * 512 * 4);
  float* ha = (float*)carve((size_t)N * 512 * 4);
  float* hb = (float*)carve((size_t)N * 512 * 4);
  float* gate = (float*)carve((size_t)N * 4);
  float* en = (float*)carve((size_t)N * 4);
  float* gmax = (float*)carve(16 * 4);
  float* gsum = (float*)carve(16 * 4);
  float* pooled = (float*)carve(512 * 4);
  (void)ws_size;

  // ---- CSR build (per launch; deterministic work) ----
  hipMemsetAsync(deg, 0, (size_t)N * 4, stream);
  hipMemsetAsync(cursor, 0, (size_t)N * 4, stream);
  hist_kernel<<<(E + 255) / 256, 256, 0, stream>>>(dst, deg, E);
  scan_kernel<<<1, 1024, 0, stream>>>(deg, offs, N);
  scatter_kernel<<<(E + 255) / 256, 256, 0, stream>>>(src, dst, offs, cursor, csr_src, E);

  // ---- layers ----
  const int fins[4] = {128, 512, 256, 64};
  const int fouts[4] = {512, 256, 64, 32};
  const int bases[4] = {3, 11, 19, 27};
  const float* hin = x;
  float* houts[4] = {ha, hb, ha, hb};

  for (int l = 0; l < 4; ++l) {
    const int fin = fins[l], fout = fouts[l];
    const float* Wq = (const float*)d_in[bases[l] + 0];
    const float* bq = (const float*)d_in[bases[l] + 1];
    const float* Wk = (const float*)d_in[bases[l] + 2];
    const float* bk = (const float*)d_in[bases[l] + 3];
    const float* Wv = (const float*)d_in[bases[l] + 4];
    const float* bv = (const float*)d_in[bases[l] + 5];
    const float* Ws = (const float*)d_in[bases[l] + 6];
    const float* bs = (const float*)d_in[bases[l] + 7];
    float* hout = houts[l];

    dim3 grid((fout + BN - 1) / BN, (N + BM - 1) / BM);
    gemm_bias_kernel<<<grid, 256, 0, stream>>>(hin, Wq, bq, qb, N, fin, fout);
    gemm_bias_kernel<<<grid, 256, 0, stream>>>(hin, Wk, bk, kb, N, fin, fout);
    gemm_bias_kernel<<<grid, 256, 0, stream>>>(hin, Wv, bv, vb, N, fin, fout);
    gemm_bias_kernel<<<grid, 256, 0, stream>>>(hin, Ws, bs, hout, N, fin, fout);

    int waves = N;
    int blocks = (waves * 64 + 255) / 256;
    attn_kernel<<<blocks, 256, 0, stream>>>(qb, kb, vb, csr_src, offs, hout, N, fout);
    hin = hout;
  }

  // ---- pooling ----
  init_pool_kernel<<<1, 512, 0, stream>>>(gmax, gsum, pooled);
  gate_kernel<<<(N + 255) / 256, 256, 0, stream>>>(hin, Wg, bg, batch, gate, gmax, N);
  expsum_kernel<<<(N + 255) / 256, 256, 0, stream>>>(gate, batch, gmax, en, gsum, N);
  poolacc_kernel<<<(N * 32 + 255) / 256, 256, 0, stream>>>(hin, batch, en, gsum, pooled, N);
  final_kernel<<<1, 192, 0, stream>>>(pooled, Wf, bf, out);
}

// Round 2
// 1159.658 us; speedup vs baseline: 1.4981x; 1.4981x over previous
//
#include <hip/hip_runtime.h>
#include <math.h>

// ---------------------------------------------------------------------------
// TransformerNet: 4x TransformerConv (heads=1) + ELU, GlobalAttention pool,
// final linear.  fp32 throughout.
// R1: attention restructured — edge-parallel logits + per-node softmax-agg
// with float4 gathers and shfl weight broadcast (was: serial per-node loop
// with recomputed dots; latency-bound at VALUBusy 25%, HBM 13%).
// ---------------------------------------------------------------------------

#define BM 64
#define BN 64
#define BK 16

// C[M,N] = A[M,K] @ W[K,N] + bias[N]
__global__ __launch_bounds__(256) void gemm_bias_kernel(
    const float* __restrict__ A, const float* __restrict__ W,
    const float* __restrict__ bias, float* __restrict__ C,
    int M, int K, int N) {
  __shared__ float As[BK][BM + 1];
  __shared__ float Ws[BK][BN];
  const int tid = threadIdx.x;
  const int bx = blockIdx.x, by = blockIdx.y;
  const int tcol = tid & 15;
  const int trow = tid >> 4;

  const int a_r = tid >> 2;
  const int a_c = (tid & 3) * 4;
  const int arow = by * BM + a_r;
  const int w_r = tid >> 4;
  const int w_c = (tid & 15) * 4;
  const int wcol = bx * BN + w_c;

  float acc[4][4];
#pragma unroll
  for (int i = 0; i < 4; ++i)
#pragma unroll
    for (int j = 0; j < 4; ++j) acc[i][j] = 0.f;

  for (int k0 = 0; k0 < K; k0 += BK) {
    float4 av = make_float4(0.f, 0.f, 0.f, 0.f);
    if (arow < M) av = *(const float4*)(A + (size_t)arow * K + k0 + a_c);
    As[a_c + 0][a_r] = av.x;
    As[a_c + 1][a_r] = av.y;
    As[a_c + 2][a_r] = av.z;
    As[a_c + 3][a_r] = av.w;

    float4 wv = make_float4(0.f, 0.f, 0.f, 0.f);
    if (wcol < N) wv = *(const float4*)(W + (size_t)(k0 + w_r) * N + wcol);
    *(float4*)&Ws[w_r][w_c] = wv;

    __syncthreads();
#pragma unroll
    for (int kk = 0; kk < BK; ++kk) {
      float a[4], b[4];
#pragma unroll
      for (int i = 0; i < 4; ++i) a[i] = As[kk][trow * 4 + i];
#pragma unroll
      for (int j = 0; j < 4; ++j) b[j] = Ws[kk][tcol * 4 + j];
#pragma unroll
      for (int i = 0; i < 4; ++i)
#pragma unroll
        for (int j = 0; j < 4; ++j) acc[i][j] += a[i] * b[j];
    }
    __syncthreads();
  }

  const int row0 = by * BM + trow * 4;
  const int col0 = bx * BN + tcol * 4;
#pragma unroll
  for (int i = 0; i < 4; ++i) {
    int r = row0 + i;
    if (r >= M) break;
#pragma unroll
    for (int j = 0; j < 4; ++j) {
      int c = col0 + j;
      if (c < N) C[(size_t)r * N + c] = acc[i][j] + bias[c];
    }
  }
}

// ---------------- CSR build ----------------
__global__ void hist_kernel(const int* __restrict__ dst, int* __restrict__ deg, int E) {
  int e = blockIdx.x * blockDim.x + threadIdx.x;
  if (e < E) atomicAdd(&deg[dst[e]], 1);
}

__global__ __launch_bounds__(1024) void scan_kernel(const int* __restrict__ deg,
                                                    int* __restrict__ offs, int N) {
  __shared__ int sums[1024];
  const int tid = threadIdx.x;
  const int chunk = (N + 1023) / 1024;
  const int start = tid * chunk;
  int s = 0;
  for (int i = 0; i < chunk; ++i) {
    int idx = start + i;
    if (idx < N) s += deg[idx];
  }
  sums[tid] = s;
  __syncthreads();
  for (int off = 1; off < 1024; off <<= 1) {
    int t = (tid >= off) ? sums[tid - off] : 0;
    __syncthreads();
    sums[tid] += t;
    __syncthreads();
  }
  int run = (tid == 0) ? 0 : sums[tid - 1];
  for (int i = 0; i < chunk; ++i) {
    int idx = start + i;
    if (idx < N) {
      offs[idx] = run;
      run += deg[idx];
    }
  }
  if (tid == 1023) offs[N] = sums[1023];
}

__global__ void scatter_kernel(const int* __restrict__ src, const int* __restrict__ dst,
                               const int* __restrict__ offs, int* __restrict__ cursor,
                               int* __restrict__ csr_src, int* __restrict__ csr_dst, int E) {
  int e = blockIdx.x * blockDim.x + threadIdx.x;
  if (e >= E) return;
  int d = dst[e];
  int pos = offs[d] + atomicAdd(&cursor[d], 1);
  csr_src[pos] = src[e];
  csr_dst[pos] = d;
}

// ---------------- edge-parallel logits (16 lanes per edge) -----------------
__global__ __launch_bounds__(256) void edge_logit_kernel(
    const float* __restrict__ q, const float* __restrict__ k,
    const int* __restrict__ csr_src, const int* __restrict__ csr_dst,
    float* __restrict__ logits, int E, int d, float scale) {
  const int g = (blockIdx.x * 256 + threadIdx.x) >> 4;
  const int l = threadIdx.x & 15;
  if (g >= E) return;
  const int s = csr_src[g];
  const int dt = csr_dst[g];
  const float4* qr = (const float4*)(q + (size_t)dt * d);
  const float4* kr = (const float4*)(k + (size_t)s * d);
  const int n4 = d >> 2;
  float p = 0.f;
  for (int i = l; i < n4; i += 16) {
    float4 a = qr[i];
    float4 b = kr[i];
    p += a.x * b.x + a.y * b.y + a.z * b.z + a.w * b.w;
  }
#pragma unroll
  for (int off = 8; off; off >>= 1) p += __shfl_xor(p, off);
  if (l == 0) logits[g] = p * scale;
}

// ---------------- per-node softmax + aggregate (one wave per node) ---------
// h_out already contains skip; writes h_out = elu(agg + skip) in place.
__global__ __launch_bounds__(256) void attn_agg_kernel(
    const float* __restrict__ v, const int* __restrict__ csr_src,
    const int* __restrict__ offs, const float* __restrict__ logits,
    float* __restrict__ h_out, int N, int d) {
  const int wid = (blockIdx.x * 256 + threadIdx.x) >> 6;
  const int lane = threadIdx.x & 63;
  if (wid >= N) return;
  const int begin = offs[wid];
  const int deg = offs[wid + 1] - begin;
  const int nj = (d + 255) >> 8;  // float4 slots per lane (d<=512 -> nj<=2)

  // max logit
  float m = -INFINITY;
  for (int c = 0; c < deg; c += 64) {
    int i = c + lane;
    if (i < deg) m = fmaxf(m, logits[begin + i]);
  }
#pragma unroll
  for (int off = 32; off; off >>= 1) m = fmaxf(m, __shfl_xor(m, off));

  float4 acc[2];
  acc[0] = make_float4(0.f, 0.f, 0.f, 0.f);
  acc[1] = make_float4(0.f, 0.f, 0.f, 0.f);
  float ssum = 0.f;

  for (int c = 0; c < deg; c += 64) {
    int i = c + lane;
    float w = 0.f;
    int s = 0;
    if (i < deg) {
      w = __expf(logits[begin + i] - m);
      s = csr_src[begin + i];
    }
    ssum += w;
    int cnt = min(64, deg - c);
    for (int e = 0; e < cnt; ++e) {
      float we = __shfl(w, e);
      int se = __shfl(s, e);
      const float4* vr = (const float4*)(v + (size_t)se * d);
#pragma unroll
      for (int j = 0; j < 2; ++j) {
        if (j < nj) {
          int f4 = lane + (j << 6);
          if ((f4 << 2) < d) {
            float4 vv = vr[f4];
            acc[j].x += we * vv.x;
            acc[j].y += we * vv.y;
            acc[j].z += we * vv.z;
            acc[j].w += we * vv.w;
          }
        }
      }
    }
  }
#pragma unroll
  for (int off = 32; off; off >>= 1) ssum += __shfl_xor(ssum, off);
  float inv = (deg > 0) ? (1.0f / ssum) : 0.f;

  float4* on = (float4*)(h_out + (size_t)wid * d);
#pragma unroll
  for (int j = 0; j < 2; ++j) {
    if (j < nj) {
      int f4 = lane + (j << 6);
      if ((f4 << 2) < d) {
        float4 sk = on[f4];
        float4 r;
        r.x = acc[j].x * inv + sk.x;
        r.y = acc[j].y * inv + sk.y;
        r.z = acc[j].z * inv + sk.z;
        r.w = acc[j].w * inv + sk.w;
        r.x = (r.x > 0.f) ? r.x : expm1f(r.x);
        r.y = (r.y > 0.f) ? r.y : expm1f(r.y);
        r.z = (r.z > 0.f) ? r.z : expm1f(r.z);
        r.w = (r.w > 0.f) ? r.w : expm1f(r.w);
        on[f4] = r;
      }
    }
  }
}

// ---------------- pooling ----------------
__device__ inline void atomicMaxFloat(float* addr, float val) {
  unsigned int* ua = (unsigned int*)addr;
  unsigned int old = *ua;
  while (true) {
    float f = __uint_as_float(old);
    if (f >= val) break;
    unsigned int assumed = old;
    old = atomicCAS(ua, assumed, __float_as_uint(val));
    if (old == assumed) break;
  }
}

__global__ void init_pool_kernel(float* gmax, float* gsum, float* pooled) {
  int t = threadIdx.x;
  if (t < 16) {
    gmax[t] = -INFINITY;
    gsum[t] = 0.f;
  }
  if (t < 512) pooled[t] = 0.f;
}

__global__ void gate_kernel(const float* __restrict__ h, const float* __restrict__ Wg,
                            const float* __restrict__ bg, const int* __restrict__ batch,
                            float* __restrict__ gate, float* __restrict__ gmax, int N) {
  int n = blockIdx.x * blockDim.x + threadIdx.x;
  if (n >= N) return;
  float g = bg[0];
  const float* hn = h + (size_t)n * 32;
#pragma unroll
  for (int i = 0; i < 32; ++i) g += hn[i] * Wg[i];
  gate[n] = g;
  atomicMaxFloat(&gmax[batch[n]], g);
}

__global__ void expsum_kernel(const float* __restrict__ gate, const int* __restrict__ batch,
                              const float* __restrict__ gmax, float* __restrict__ en,
                              float* __restrict__ gsum, int N) {
  int n = blockIdx.x * blockDim.x + threadIdx.x;
  if (n >= N) return;
  int b = batch[n];
  float e = expf(gate[n] - gmax[b]);
  en[n] = e;
  atomicAdd(&gsum[b], e);
}

__global__ void poolacc_kernel(const float* __restrict__ h, const int* __restrict__ batch,
                               const float* __restrict__ en, const float* __restrict__ gsum,
                               float* __restrict__ pooled, int N) {
  int idx = blockIdx.x * blockDim.x + threadIdx.x;
  if (idx >= N * 32) return;
  int n = idx >> 5;
  int i = idx & 31;
  int b = batch[n];
  float a = en[n] / gsum[b];
  atomicAdd(&pooled[b * 32 + i], a * h[(size_t)n * 32 + i]);
}

__global__ void final_kernel(const float* __restrict__ pooled, const float* __restrict__ Wf,
                             const float* __restrict__ bf, float* __restrict__ out) {
  int t = threadIdx.x;
  if (t >= 16 * 9) return;
  int g = t / 9;
  int j = t % 9;
  float s = bf[j];
#pragma unroll
  for (int kk = 0; kk < 32; ++kk) s += pooled[g * 32 + kk] * Wf[kk * 9 + j];
  out[g * 9 + j] = s;
}

// ---------------------------------------------------------------------------
extern "C" void kernel_launch(void* const* d_in, const int* in_sizes, int n_in,
                              void* d_out, int out_size, void* d_ws, size_t ws_size,
                              hipStream_t stream) {
  const int N = in_sizes[2];       // 10000 nodes
  const int E = in_sizes[1] / 2;   // 160000 edges

  const float* x = (const float*)d_in[0];
  const int* ei = (const int*)d_in[1];
  const int* batch = (const int*)d_in[2];
  const int* src = ei;
  const int* dst = ei + E;
  const float* Wg = (const float*)d_in[35];
  const float* bg = (const float*)d_in[36];
  const float* Wf = (const float*)d_in[37];
  const float* bf = (const float*)d_in[38];
  float* out = (float*)d_out;

  char* p = (char*)d_ws;
  auto carve = [&](size_t bytes) -> char* {
    char* r = p;
    p += (bytes + 255) & ~(size_t)255;
    return r;
  };
  int* deg = (int*)carve((size_t)N * 4);
  int* offs = (int*)carve((size_t)(N + 1) * 4);
  int* cursor = (int*)carve((size_t)N * 4);
  int* csr_src = (int*)carve((size_t)E * 4);
  int* csr_dst = (int*)carve((size_t)E * 4);
  float* logits = (float*)carve((size_t)E * 4);
  float* qb = (float*)carve((size_t)N * 512 * 4);
  float* kb = (float*)carve((size_t)N * 512 * 4);
  float* vb = (float*)carve((size_t)N * 512 * 4);
  float* ha = (float*)carve((size_t)N * 512 * 4);
  float* hb = (float*)carve((size_t)N * 512 * 4);
  float* gate = (float*)carve((size_t)N * 4);
  float* en = (float*)carve((size_t)N * 4);
  float* gmax = (float*)carve(16 * 4);
  float* gsum = (float*)carve(16 * 4);
  float* pooled = (float*)carve(512 * 4);
  (void)ws_size;

  // ---- CSR build ----
  hipMemsetAsync(deg, 0, (size_t)N * 4, stream);
  hipMemsetAsync(cursor, 0, (size_t)N * 4, stream);
  hist_kernel<<<(E + 255) / 256, 256, 0, stream>>>(dst, deg, E);
  scan_kernel<<<1, 1024, 0, stream>>>(deg, offs, N);
  scatter_kernel<<<(E + 255) / 256, 256, 0, stream>>>(src, dst, offs, cursor, csr_src, csr_dst, E);

  // ---- layers ----
  const int fins[4] = {128, 512, 256, 64};
  const int fouts[4] = {512, 256, 64, 32};
  const int bases[4] = {3, 11, 19, 27};
  const float* hin = x;
  float* houts[4] = {ha, hb, ha, hb};

  for (int l = 0; l < 4; ++l) {
    const int fin = fins[l], fout = fouts[l];
    const float* Wq = (const float*)d_in[bases[l] + 0];
    const float* bq = (const float*)d_in[bases[l] + 1];
    const float* Wk = (const float*)d_in[bases[l] + 2];
    const float* bk = (const float*)d_in[bases[l] + 3];
    const float* Wv = (const float*)d_in[bases[l] + 4];
    const float* bv = (const float*)d_in[bases[l] + 5];
    const float* Ws = (const float*)d_in[bases[l] + 6];
    const float* bs = (const float*)d_in[bases[l] + 7];
    float* hout = houts[l];

    dim3 grid((fout + BN - 1) / BN, (N + BM - 1) / BM);
    gemm_bias_kernel<<<grid, 256, 0, stream>>>(hin, Wq, bq, qb, N, fin, fout);
    gemm_bias_kernel<<<grid, 256, 0, stream>>>(hin, Wk, bk, kb, N, fin, fout);
    gemm_bias_kernel<<<grid, 256, 0, stream>>>(hin, Wv, bv, vb, N, fin, fout);
    gemm_bias_kernel<<<grid, 256, 0, stream>>>(hin, Ws, bs, hout, N, fin, fout);

    float scale = 1.0f / sqrtf((float)fout);
    edge_logit_kernel<<<((size_t)E * 16 + 255) / 256, 256, 0, stream>>>(
        qb, kb, csr_src, csr_dst, logits, E, fout, scale);
    attn_agg_kernel<<<(N * 64 + 255) / 256, 256, 0, stream>>>(
        vb, csr_src, offs, logits, hout, N, fout);
    hin = hout;
  }

  // ---- pooling ----
  init_pool_kernel<<<1, 512, 0, stream>>>(gmax, gsum, pooled);
  gate_kernel<<<(N + 255) / 256, 256, 0, stream>>>(hin, Wg, bg, batch, gate, gmax, N);
  expsum_kernel<<<(N + 255) / 256, 256, 0, stream>>>(gate, batch, gmax, en, gsum, N);
  poolacc_kernel<<<(N * 32 + 255) / 256, 256, 0, stream>>>(hin, batch, en, gsum, pooled, N);
  final_kernel<<<1, 192, 0, stream>>>(pooled, Wf, bf, out);
}

// Round 3
// 834.874 us; speedup vs baseline: 2.0809x; 1.3890x over previous
//
#include <hip/hip_runtime.h>
#include <math.h>

// ---------------------------------------------------------------------------
// TransformerNet: 4x TransformerConv (heads=1) + ELU, GlobalAttention pool,
// final linear.  fp32 throughout.
// R1: edge-parallel logits + per-node softmax-agg (float4 gathers).
// R2: pooling atomics eliminated — gate_kernel's atomicCAS-max over 16 words
//     was 210us at 0.007% VALUBusy (pure contention). batch is sorted, so:
//     binary-search graph bounds + one block/graph LDS-reduced pool+final.
// ---------------------------------------------------------------------------

#define BM 64
#define BN 64
#define BK 16

// C[M,N] = A[M,K] @ W[K,N] + bias[N]
__global__ __launch_bounds__(256) void gemm_bias_kernel(
    const float* __restrict__ A, const float* __restrict__ W,
    const float* __restrict__ bias, float* __restrict__ C,
    int M, int K, int N) {
  __shared__ float As[BK][BM + 1];
  __shared__ float Ws[BK][BN];
  const int tid = threadIdx.x;
  const int bx = blockIdx.x, by = blockIdx.y;
  const int tcol = tid & 15;
  const int trow = tid >> 4;

  const int a_r = tid >> 2;
  const int a_c = (tid & 3) * 4;
  const int arow = by * BM + a_r;
  const int w_r = tid >> 4;
  const int w_c = (tid & 15) * 4;
  const int wcol = bx * BN + w_c;

  float acc[4][4];
#pragma unroll
  for (int i = 0; i < 4; ++i)
#pragma unroll
    for (int j = 0; j < 4; ++j) acc[i][j] = 0.f;

  for (int k0 = 0; k0 < K; k0 += BK) {
    float4 av = make_float4(0.f, 0.f, 0.f, 0.f);
    if (arow < M) av = *(const float4*)(A + (size_t)arow * K + k0 + a_c);
    As[a_c + 0][a_r] = av.x;
    As[a_c + 1][a_r] = av.y;
    As[a_c + 2][a_r] = av.z;
    As[a_c + 3][a_r] = av.w;

    float4 wv = make_float4(0.f, 0.f, 0.f, 0.f);
    if (wcol < N) wv = *(const float4*)(W + (size_t)(k0 + w_r) * N + wcol);
    *(float4*)&Ws[w_r][w_c] = wv;

    __syncthreads();
#pragma unroll
    for (int kk = 0; kk < BK; ++kk) {
      float a[4], b[4];
#pragma unroll
      for (int i = 0; i < 4; ++i) a[i] = As[kk][trow * 4 + i];
#pragma unroll
      for (int j = 0; j < 4; ++j) b[j] = Ws[kk][tcol * 4 + j];
#pragma unroll
      for (int i = 0; i < 4; ++i)
#pragma unroll
        for (int j = 0; j < 4; ++j) acc[i][j] += a[i] * b[j];
    }
    __syncthreads();
  }

  const int row0 = by * BM + trow * 4;
  const int col0 = bx * BN + tcol * 4;
#pragma unroll
  for (int i = 0; i < 4; ++i) {
    int r = row0 + i;
    if (r >= M) break;
#pragma unroll
    for (int j = 0; j < 4; ++j) {
      int c = col0 + j;
      if (c < N) C[(size_t)r * N + c] = acc[i][j] + bias[c];
    }
  }
}

// ---------------- CSR build ----------------
__global__ void hist_kernel(const int* __restrict__ dst, int* __restrict__ deg, int E) {
  int e = blockIdx.x * blockDim.x + threadIdx.x;
  if (e < E) atomicAdd(&deg[dst[e]], 1);
}

__global__ __launch_bounds__(1024) void scan_kernel(const int* __restrict__ deg,
                                                    int* __restrict__ offs, int N) {
  __shared__ int sums[1024];
  const int tid = threadIdx.x;
  const int chunk = (N + 1023) / 1024;
  const int start = tid * chunk;
  int s = 0;
  for (int i = 0; i < chunk; ++i) {
    int idx = start + i;
    if (idx < N) s += deg[idx];
  }
  sums[tid] = s;
  __syncthreads();
  for (int off = 1; off < 1024; off <<= 1) {
    int t = (tid >= off) ? sums[tid - off] : 0;
    __syncthreads();
    sums[tid] += t;
    __syncthreads();
  }
  int run = (tid == 0) ? 0 : sums[tid - 1];
  for (int i = 0; i < chunk; ++i) {
    int idx = start + i;
    if (idx < N) {
      offs[idx] = run;
      run += deg[idx];
    }
  }
  if (tid == 1023) offs[N] = sums[1023];
}

__global__ void scatter_kernel(const int* __restrict__ src, const int* __restrict__ dst,
                               const int* __restrict__ offs, int* __restrict__ cursor,
                               int* __restrict__ csr_src, int* __restrict__ csr_dst, int E) {
  int e = blockIdx.x * blockDim.x + threadIdx.x;
  if (e >= E) return;
  int d = dst[e];
  int pos = offs[d] + atomicAdd(&cursor[d], 1);
  csr_src[pos] = src[e];
  csr_dst[pos] = d;
}

// ---------------- edge-parallel logits (16 lanes per edge) -----------------
__global__ __launch_bounds__(256) void edge_logit_kernel(
    const float* __restrict__ q, const float* __restrict__ k,
    const int* __restrict__ csr_src, const int* __restrict__ csr_dst,
    float* __restrict__ logits, int E, int d, float scale) {
  const int g = (blockIdx.x * 256 + threadIdx.x) >> 4;
  const int l = threadIdx.x & 15;
  if (g >= E) return;
  const int s = csr_src[g];
  const int dt = csr_dst[g];
  const float4* qr = (const float4*)(q + (size_t)dt * d);
  const float4* kr = (const float4*)(k + (size_t)s * d);
  const int n4 = d >> 2;
  float p = 0.f;
  for (int i = l; i < n4; i += 16) {
    float4 a = qr[i];
    float4 b = kr[i];
    p += a.x * b.x + a.y * b.y + a.z * b.z + a.w * b.w;
  }
#pragma unroll
  for (int off = 8; off; off >>= 1) p += __shfl_xor(p, off);
  if (l == 0) logits[g] = p * scale;
}

// ---------------- per-node softmax + aggregate (one wave per node) ---------
__global__ __launch_bounds__(256) void attn_agg_kernel(
    const float* __restrict__ v, const int* __restrict__ csr_src,
    const int* __restrict__ offs, const float* __restrict__ logits,
    float* __restrict__ h_out, int N, int d) {
  const int wid = (blockIdx.x * 256 + threadIdx.x) >> 6;
  const int lane = threadIdx.x & 63;
  if (wid >= N) return;
  const int begin = offs[wid];
  const int deg = offs[wid + 1] - begin;
  const int nj = (d + 255) >> 8;

  float m = -INFINITY;
  for (int c = 0; c < deg; c += 64) {
    int i = c + lane;
    if (i < deg) m = fmaxf(m, logits[begin + i]);
  }
#pragma unroll
  for (int off = 32; off; off >>= 1) m = fmaxf(m, __shfl_xor(m, off));

  float4 acc[2];
  acc[0] = make_float4(0.f, 0.f, 0.f, 0.f);
  acc[1] = make_float4(0.f, 0.f, 0.f, 0.f);
  float ssum = 0.f;

  for (int c = 0; c < deg; c += 64) {
    int i = c + lane;
    float w = 0.f;
    int s = 0;
    if (i < deg) {
      w = __expf(logits[begin + i] - m);
      s = csr_src[begin + i];
    }
    ssum += w;
    int cnt = min(64, deg - c);
    for (int e = 0; e < cnt; ++e) {
      float we = __shfl(w, e);
      int se = __shfl(s, e);
      const float4* vr = (const float4*)(v + (size_t)se * d);
#pragma unroll
      for (int j = 0; j < 2; ++j) {
        if (j < nj) {
          int f4 = lane + (j << 6);
          if ((f4 << 2) < d) {
            float4 vv = vr[f4];
            acc[j].x += we * vv.x;
            acc[j].y += we * vv.y;
            acc[j].z += we * vv.z;
            acc[j].w += we * vv.w;
          }
        }
      }
    }
  }
#pragma unroll
  for (int off = 32; off; off >>= 1) ssum += __shfl_xor(ssum, off);
  float inv = (deg > 0) ? (1.0f / ssum) : 0.f;

  float4* on = (float4*)(h_out + (size_t)wid * d);
#pragma unroll
  for (int j = 0; j < 2; ++j) {
    if (j < nj) {
      int f4 = lane + (j << 6);
      if ((f4 << 2) < d) {
        float4 sk = on[f4];
        float4 r;
        r.x = acc[j].x * inv + sk.x;
        r.y = acc[j].y * inv + sk.y;
        r.z = acc[j].z * inv + sk.z;
        r.w = acc[j].w * inv + sk.w;
        r.x = (r.x > 0.f) ? r.x : expm1f(r.x);
        r.y = (r.y > 0.f) ? r.y : expm1f(r.y);
        r.z = (r.z > 0.f) ? r.z : expm1f(r.z);
        r.w = (r.w > 0.f) ? r.w : expm1f(r.w);
        on[f4] = r;
      }
    }
  }
}

// ---------------- pooling (atomic-free) ----------------
// gate[n] = h[n,:32] @ Wg + bg   (no atomics)
__global__ void gate_kernel(const float* __restrict__ h, const float* __restrict__ Wg,
                            const float* __restrict__ bg, float* __restrict__ gate, int N) {
  int n = blockIdx.x * blockDim.x + threadIdx.x;
  if (n >= N) return;
  const float4* hn = (const float4*)(h + (size_t)n * 32);
  const float4* wg = (const float4*)Wg;
  float g = bg[0];
#pragma unroll
  for (int i = 0; i < 8; ++i) {
    float4 a = hn[i];
    float4 b = wg[i];
    g += a.x * b.x + a.y * b.y + a.z * b.z + a.w * b.w;
  }
  gate[n] = g;
}

// bounds[g] = first index with batch[i] >= g  (batch sorted), bounds[G]=N
__global__ void bounds_kernel(const int* __restrict__ batch, int* __restrict__ bounds,
                              int N, int G) {
  int g = threadIdx.x;
  if (g > G) return;
  int lo = 0, hi = N;
  while (lo < hi) {
    int mid = (lo + hi) >> 1;
    if (batch[mid] < g) lo = mid + 1;
    else hi = mid;
  }
  bounds[g] = lo;
}

// one block per graph: softmax over gate, weighted sum of h, final 32->9.
__global__ __launch_bounds__(256) void pool_final_kernel(
    const float* __restrict__ h, const float* __restrict__ gate,
    const int* __restrict__ bounds, const float* __restrict__ Wf,
    const float* __restrict__ bf, float* __restrict__ out) {
  __shared__ float red[256];
  __shared__ float pooled_s[32];
  __shared__ float m_s, inv_s;
  const int g = blockIdx.x;
  const int tid = threadIdx.x;
  const int s = bounds[g];
  const int e_end = bounds[g + 1];

  // pass 1: max
  float m = -INFINITY;
  for (int i = s + tid; i < e_end; i += 256) m = fmaxf(m, gate[i]);
  red[tid] = m;
  __syncthreads();
  for (int off = 128; off; off >>= 1) {
    if (tid < off) red[tid] = fmaxf(red[tid], red[tid + off]);
    __syncthreads();
  }
  if (tid == 0) m_s = red[0];
  __syncthreads();
  m = m_s;

  // pass 2: exp-sum
  float ss = 0.f;
  for (int i = s + tid; i < e_end; i += 256) ss += __expf(gate[i] - m);
  red[tid] = ss;
  __syncthreads();
  for (int off = 128; off; off >>= 1) {
    if (tid < off) red[tid] += red[tid + off];
    __syncthreads();
  }
  if (tid == 0) inv_s = (e_end > s) ? (1.0f / red[0]) : 0.f;
  __syncthreads();
  const float inv = inv_s;

  // pass 3: weighted feature sum. thread = (group 0..7, feature 0..31)
  const int f = tid & 31;
  const int grp = tid >> 5;
  float acc = 0.f;
  for (int i = s + grp; i < e_end; i += 8)
    acc += __expf(gate[i] - m) * h[(size_t)i * 32 + f];
  red[tid] = acc;
  __syncthreads();
  if (tid < 32) {
    float a = 0.f;
#pragma unroll
    for (int j = 0; j < 8; ++j) a += red[j * 32 + tid];
    pooled_s[tid] = a * inv;
  }
  __syncthreads();

  // final: out[g, 0..8]
  if (tid < 9) {
    float o = bf[tid];
#pragma unroll
    for (int kk = 0; kk < 32; ++kk) o += pooled_s[kk] * Wf[kk * 9 + tid];
    out[g * 9 + tid] = o;
  }
}

// ---------------------------------------------------------------------------
extern "C" void kernel_launch(void* const* d_in, const int* in_sizes, int n_in,
                              void* d_out, int out_size, void* d_ws, size_t ws_size,
                              hipStream_t stream) {
  const int N = in_sizes[2];       // 10000 nodes
  const int E = in_sizes[1] / 2;   // 160000 edges
  const int G = 16;

  const float* x = (const float*)d_in[0];
  const int* ei = (const int*)d_in[1];
  const int* batch = (const int*)d_in[2];
  const int* src = ei;
  const int* dst = ei + E;
  const float* Wg = (const float*)d_in[35];
  const float* bg = (const float*)d_in[36];
  const float* Wf = (const float*)d_in[37];
  const float* bf = (const float*)d_in[38];
  float* out = (float*)d_out;

  char* p = (char*)d_ws;
  auto carve = [&](size_t bytes) -> char* {
    char* r = p;
    p += (bytes + 255) & ~(size_t)255;
    return r;
  };
  int* deg = (int*)carve((size_t)N * 4);
  int* offs = (int*)carve((size_t)(N + 1) * 4);
  int* cursor = (int*)carve((size_t)N * 4);
  int* csr_src = (int*)carve((size_t)E * 4);
  int* csr_dst = (int*)carve((size_t)E * 4);
  float* logits = (float*)carve((size_t)E * 4);
  float* qb = (float*)carve((size_t)N * 512 * 4);
  float* kb = (float*)carve((size_t)N * 512 * 4);
  float* vb = (float*)carve((size_t)N * 512 * 4);
  float* ha = (float*)carve((size_t)N * 512 * 4);
  float* hb = (float*)carve((size_t)N * 512 * 4);
  float* gate = (float*)carve((size_t)N * 4);
  int* bounds = (int*)carve((size_t)(G + 1) * 4);
  (void)ws_size;

  // ---- CSR build ----
  hipMemsetAsync(deg, 0, (size_t)N * 4, stream);
  hipMemsetAsync(cursor, 0, (size_t)N * 4, stream);
  hist_kernel<<<(E + 255) / 256, 256, 0, stream>>>(dst, deg, E);
  scan_kernel<<<1, 1024, 0, stream>>>(deg, offs, N);
  scatter_kernel<<<(E + 255) / 256, 256, 0, stream>>>(src, dst, offs, cursor, csr_src, csr_dst, E);

  // ---- layers ----
  const int fins[4] = {128, 512, 256, 64};
  const int fouts[4] = {512, 256, 64, 32};
  const int bases[4] = {3, 11, 19, 27};
  const float* hin = x;
  float* houts[4] = {ha, hb, ha, hb};

  for (int l = 0; l < 4; ++l) {
    const int fin = fins[l], fout = fouts[l];
    const float* Wq = (const float*)d_in[bases[l] + 0];
    const float* bq = (const float*)d_in[bases[l] + 1];
    const float* Wk = (const float*)d_in[bases[l] + 2];
    const float* bk = (const float*)d_in[bases[l] + 3];
    const float* Wv = (const float*)d_in[bases[l] + 4];
    const float* bv = (const float*)d_in[bases[l] + 5];
    const float* Ws = (const float*)d_in[bases[l] + 6];
    const float* bs = (const float*)d_in[bases[l] + 7];
    float* hout = houts[l];

    dim3 grid((fout + BN - 1) / BN, (N + BM - 1) / BM);
    gemm_bias_kernel<<<grid, 256, 0, stream>>>(hin, Wq, bq, qb, N, fin, fout);
    gemm_bias_kernel<<<grid, 256, 0, stream>>>(hin, Wk, bk, kb, N, fin, fout);
    gemm_bias_kernel<<<grid, 256, 0, stream>>>(hin, Wv, bv, vb, N, fin, fout);
    gemm_bias_kernel<<<grid, 256, 0, stream>>>(hin, Ws, bs, hout, N, fin, fout);

    float scale = 1.0f / sqrtf((float)fout);
    edge_logit_kernel<<<((size_t)E * 16 + 255) / 256, 256, 0, stream>>>(
        qb, kb, csr_src, csr_dst, logits, E, fout, scale);
    attn_agg_kernel<<<(N * 64 + 255) / 256, 256, 0, stream>>>(
        vb, csr_src, offs, logits, hout, N, fout);
    hin = hout;
  }

  // ---- pooling (atomic-free) ----
  gate_kernel<<<(N + 255) / 256, 256, 0, stream>>>(hin, Wg, bg, gate, N);
  bounds_kernel<<<1, G + 1, 0, stream>>>(batch, bounds, N, G);
  pool_final_kernel<<<G, 256, 0, stream>>>(hin, gate, bounds, Wf, bf, out);
}

// Round 4
// 500.438 us; speedup vs baseline: 3.4715x; 1.6683x over previous
//
#include <hip/hip_runtime.h>
#include <hip/hip_bf16.h>
#include <math.h>

// ---------------------------------------------------------------------------
// TransformerNet: 4x TransformerConv (heads=1) + ELU, GlobalAttention pool,
// final linear.
// R1: edge-parallel logits + per-node softmax-agg (float4 gathers).
// R2: atomic-free pooling (sorted batch -> binary-search bounds).
// R3: GEMMs -> bf16 MFMA (16x16x32, fp32 acc), q|k|v|s fused into ONE GEMM
//     per layer via per-launch packed transposed bf16 weights. fp32 path was
//     42 TF / VALUBusy 30% / 643k LDS conflicts; no fp32 MFMA on CDNA4.
// ---------------------------------------------------------------------------

typedef __bf16 bf16x8 __attribute__((ext_vector_type(8)));
typedef __bf16 bf16x4v __attribute__((ext_vector_type(4)));
typedef float f32x4 __attribute__((ext_vector_type(4)));

#define GBM 128
#define GBN 128
#define GBK 32
#define LDP 40  // LDS row stride in bf16 (20 words -> 2-way bank alias, free)

// C[M,N] = A[M,K](bf16) @ Bt[N,K](bf16)^T + bias[N], fp32 out.
__global__ __launch_bounds__(256) void gemm_mfma_kernel(
    const __bf16* __restrict__ A, const __bf16* __restrict__ Bt,
    const float* __restrict__ bias, float* __restrict__ C,
    int M, int K, int N) {
  __shared__ __bf16 As[GBM * LDP];
  __shared__ __bf16 Bs[GBN * LDP];
  const int tid = threadIdx.x;
  const int wave = tid >> 6;
  const int lane = tid & 63;
  const int quad = lane >> 4;
  const int l16 = lane & 15;
  const int m0 = blockIdx.y * GBM;
  const int n0 = blockIdx.x * GBN;
  const int wm = (wave & 1) * 64;
  const int wn = (wave >> 1) * 64;

  f32x4 acc[4][4] = {};

  for (int k0 = 0; k0 < K; k0 += GBK) {
    // stage 128x32 A-tile and B-tile: 512 chunks of 8 bf16 each, 2 iters
#pragma unroll
    for (int it = 0; it < 2; ++it) {
      int idx = tid + it * 256;
      int row = idx >> 2, seg = idx & 3;
      bf16x8 av = {};
      int gr = m0 + row;
      if (gr < M) av = *(const bf16x8*)(A + (size_t)gr * K + k0 + seg * 8);
      *(bf16x8*)(As + row * LDP + seg * 8) = av;
      bf16x8 bv = *(const bf16x8*)(Bt + (size_t)(n0 + row) * K + k0 + seg * 8);
      *(bf16x8*)(Bs + row * LDP + seg * 8) = bv;
    }
    __syncthreads();

    bf16x8 af[4], bfr[4];
#pragma unroll
    for (int i = 0; i < 4; ++i) {
      af[i]  = *(const bf16x8*)(As + (wm + i * 16 + l16) * LDP + quad * 8);
      bfr[i] = *(const bf16x8*)(Bs + (wn + i * 16 + l16) * LDP + quad * 8);
    }
#pragma unroll
    for (int mi = 0; mi < 4; ++mi)
#pragma unroll
      for (int ni = 0; ni < 4; ++ni)
        acc[mi][ni] = __builtin_amdgcn_mfma_f32_16x16x32_bf16(
            af[mi], bfr[ni], acc[mi][ni], 0, 0, 0);
    __syncthreads();
  }

  // C/D layout: col = lane&15, row = quad*4 + reg   [m89-verified]
#pragma unroll
  for (int mi = 0; mi < 4; ++mi) {
#pragma unroll
    for (int r = 0; r < 4; ++r) {
      int row = m0 + wm + mi * 16 + quad * 4 + r;
      if (row < M) {
#pragma unroll
        for (int ni = 0; ni < 4; ++ni) {
          int col = n0 + wn + ni * 16 + l16;
          C[(size_t)row * N + col] = acc[mi][ni][r] + bias[col];
        }
      }
    }
  }
}

// pack 4 fp32 weight matrices [K,fout] -> transposed bf16 Wt[4*fout][K]; concat biases.
__global__ void pack_w_kernel(const float* __restrict__ Wq, const float* __restrict__ Wk,
                              const float* __restrict__ Wv, const float* __restrict__ Ws,
                              const float* __restrict__ bq, const float* __restrict__ bk,
                              const float* __restrict__ bv, const float* __restrict__ bs,
                              __bf16* __restrict__ Wt, float* __restrict__ bcat,
                              int K, int fout) {
  int total = 4 * fout * K;
  int tid = blockIdx.x * blockDim.x + threadIdx.x;
  if (tid < total) {
    int c = tid / K;
    int kk = tid - c * K;
    int blk = c / fout;
    int j = c - blk * fout;
    const float* W = blk == 0 ? Wq : blk == 1 ? Wk : blk == 2 ? Wv : Ws;
    Wt[tid] = (__bf16)W[(size_t)kk * fout + j];
  }
  if (tid < 4 * fout) {
    int blk = tid / fout, j = tid - blk * fout;
    const float* b = blk == 0 ? bq : blk == 1 ? bk : blk == 2 ? bv : bs;
    bcat[tid] = b[j];
  }
}

// fp32 -> bf16 cast, 4 elems/thread
__global__ void cast_bf16_kernel(const float* __restrict__ in, __bf16* __restrict__ out,
                                 int n4) {
  int i = blockIdx.x * blockDim.x + threadIdx.x;
  if (i >= n4) return;
  float4 v = ((const float4*)in)[i];
  bf16x4v o;
  o[0] = (__bf16)v.x; o[1] = (__bf16)v.y; o[2] = (__bf16)v.z; o[3] = (__bf16)v.w;
  *(bf16x4v*)(out + (size_t)i * 4) = o;
}

// ---------------- CSR build ----------------
__global__ void hist_kernel(const int* __restrict__ dst, int* __restrict__ deg, int E) {
  int e = blockIdx.x * blockDim.x + threadIdx.x;
  if (e < E) atomicAdd(&deg[dst[e]], 1);
}

__global__ __launch_bounds__(1024) void scan_kernel(const int* __restrict__ deg,
                                                    int* __restrict__ offs, int N) {
  __shared__ int sums[1024];
  const int tid = threadIdx.x;
  const int chunk = (N + 1023) / 1024;
  const int start = tid * chunk;
  int s = 0;
  for (int i = 0; i < chunk; ++i) {
    int idx = start + i;
    if (idx < N) s += deg[idx];
  }
  sums[tid] = s;
  __syncthreads();
  for (int off = 1; off < 1024; off <<= 1) {
    int t = (tid >= off) ? sums[tid - off] : 0;
    __syncthreads();
    sums[tid] += t;
    __syncthreads();
  }
  int run = (tid == 0) ? 0 : sums[tid - 1];
  for (int i = 0; i < chunk; ++i) {
    int idx = start + i;
    if (idx < N) {
      offs[idx] = run;
      run += deg[idx];
    }
  }
  if (tid == 1023) offs[N] = sums[1023];
}

__global__ void scatter_kernel(const int* __restrict__ src, const int* __restrict__ dst,
                               const int* __restrict__ offs, int* __restrict__ cursor,
                               int* __restrict__ csr_src, int* __restrict__ csr_dst, int E) {
  int e = blockIdx.x * blockDim.x + threadIdx.x;
  if (e >= E) return;
  int d = dst[e];
  int pos = offs[d] + atomicAdd(&cursor[d], 1);
  csr_src[pos] = src[e];
  csr_dst[pos] = d;
}

// ---------------- edge-parallel logits (16 lanes per edge) -----------------
// q at qkvs[.,0:fout], k at qkvs[.,fout:2fout]; row stride ld.
__global__ __launch_bounds__(256) void edge_logit_kernel(
    const float* __restrict__ qkvs, const int* __restrict__ csr_src,
    const int* __restrict__ csr_dst, float* __restrict__ logits,
    int E, int d, int ld, float scale) {
  const int g = (blockIdx.x * 256 + threadIdx.x) >> 4;
  const int l = threadIdx.x & 15;
  if (g >= E) return;
  const int s = csr_src[g];
  const int dt = csr_dst[g];
  const float4* qr = (const float4*)(qkvs + (size_t)dt * ld);
  const float4* kr = (const float4*)(qkvs + (size_t)s * ld + d);
  const int n4 = d >> 2;
  float p = 0.f;
  for (int i = l; i < n4; i += 16) {
    float4 a = qr[i];
    float4 b = kr[i];
    p += a.x * b.x + a.y * b.y + a.z * b.z + a.w * b.w;
  }
#pragma unroll
  for (int off = 8; off; off >>= 1) p += __shfl_xor(p, off);
  if (l == 0) logits[g] = p * scale;
}

// ---------------- per-node softmax + aggregate (one wave per node) ---------
// v at qkvs[.,2fout:3fout], skip at qkvs[.,3fout:4fout]; writes compact h_out.
__global__ __launch_bounds__(256) void attn_agg_kernel(
    const float* __restrict__ qkvs, const int* __restrict__ csr_src,
    const int* __restrict__ offs, const float* __restrict__ logits,
    float* __restrict__ h_out, int N, int d, int ld) {
  const int wid = (blockIdx.x * 256 + threadIdx.x) >> 6;
  const int lane = threadIdx.x & 63;
  if (wid >= N) return;
  const int begin = offs[wid];
  const int deg = offs[wid + 1] - begin;
  const int nj = (d + 255) >> 8;

  float m = -INFINITY;
  for (int c = 0; c < deg; c += 64) {
    int i = c + lane;
    if (i < deg) m = fmaxf(m, logits[begin + i]);
  }
#pragma unroll
  for (int off = 32; off; off >>= 1) m = fmaxf(m, __shfl_xor(m, off));

  float4 acc[2];
  acc[0] = make_float4(0.f, 0.f, 0.f, 0.f);
  acc[1] = make_float4(0.f, 0.f, 0.f, 0.f);
  float ssum = 0.f;

  const float* vbase = qkvs + 2 * (size_t)d;
  for (int c = 0; c < deg; c += 64) {
    int i = c + lane;
    float w = 0.f;
    int s = 0;
    if (i < deg) {
      w = __expf(logits[begin + i] - m);
      s = csr_src[begin + i];
    }
    ssum += w;
    int cnt = min(64, deg - c);
    for (int e = 0; e < cnt; ++e) {
      float we = __shfl(w, e);
      int se = __shfl(s, e);
      const float4* vr = (const float4*)(vbase + (size_t)se * ld);
#pragma unroll
      for (int j = 0; j < 2; ++j) {
        if (j < nj) {
          int f4 = lane + (j << 6);
          if ((f4 << 2) < d) {
            float4 vv = vr[f4];
            acc[j].x += we * vv.x;
            acc[j].y += we * vv.y;
            acc[j].z += we * vv.z;
            acc[j].w += we * vv.w;
          }
        }
      }
    }
  }
#pragma unroll
  for (int off = 32; off; off >>= 1) ssum += __shfl_xor(ssum, off);
  float inv = (deg > 0) ? (1.0f / ssum) : 0.f;

  const float4* sk4 = (const float4*)(qkvs + (size_t)wid * ld + 3 * (size_t)d);
  float4* on = (float4*)(h_out + (size_t)wid * d);
#pragma unroll
  for (int j = 0; j < 2; ++j) {
    if (j < nj) {
      int f4 = lane + (j << 6);
      if ((f4 << 2) < d) {
        float4 sk = sk4[f4];
        float4 r;
        r.x = acc[j].x * inv + sk.x;
        r.y = acc[j].y * inv + sk.y;
        r.z = acc[j].z * inv + sk.z;
        r.w = acc[j].w * inv + sk.w;
        r.x = (r.x > 0.f) ? r.x : expm1f(r.x);
        r.y = (r.y > 0.f) ? r.y : expm1f(r.y);
        r.z = (r.z > 0.f) ? r.z : expm1f(r.z);
        r.w = (r.w > 0.f) ? r.w : expm1f(r.w);
        on[f4] = r;
      }
    }
  }
}

// ---------------- pooling (atomic-free) ----------------
__global__ void gate_kernel(const float* __restrict__ h, const float* __restrict__ Wg,
                            const float* __restrict__ bg, float* __restrict__ gate, int N) {
  int n = blockIdx.x * blockDim.x + threadIdx.x;
  if (n >= N) return;
  const float4* hn = (const float4*)(h + (size_t)n * 32);
  const float4* wg = (const float4*)Wg;
  float g = bg[0];
#pragma unroll
  for (int i = 0; i < 8; ++i) {
    float4 a = hn[i];
    float4 b = wg[i];
    g += a.x * b.x + a.y * b.y + a.z * b.z + a.w * b.w;
  }
  gate[n] = g;
}

__global__ void bounds_kernel(const int* __restrict__ batch, int* __restrict__ bounds,
                              int N, int G) {
  int g = threadIdx.x;
  if (g > G) return;
  int lo = 0, hi = N;
  while (lo < hi) {
    int mid = (lo + hi) >> 1;
    if (batch[mid] < g) lo = mid + 1;
    else hi = mid;
  }
  bounds[g] = lo;
}

__global__ __launch_bounds__(256) void pool_final_kernel(
    const float* __restrict__ h, const float* __restrict__ gate,
    const int* __restrict__ bounds, const float* __restrict__ Wf,
    const float* __restrict__ bf_, float* __restrict__ out) {
  __shared__ float red[256];
  __shared__ float pooled_s[32];
  __shared__ float m_s, inv_s;
  const int g = blockIdx.x;
  const int tid = threadIdx.x;
  const int s = bounds[g];
  const int e_end = bounds[g + 1];

  float m = -INFINITY;
  for (int i = s + tid; i < e_end; i += 256) m = fmaxf(m, gate[i]);
  red[tid] = m;
  __syncthreads();
  for (int off = 128; off; off >>= 1) {
    if (tid < off) red[tid] = fmaxf(red[tid], red[tid + off]);
    __syncthreads();
  }
  if (tid == 0) m_s = red[0];
  __syncthreads();
  m = m_s;

  float ss = 0.f;
  for (int i = s + tid; i < e_end; i += 256) ss += __expf(gate[i] - m);
  red[tid] = ss;
  __syncthreads();
  for (int off = 128; off; off >>= 1) {
    if (tid < off) red[tid] += red[tid + off];
    __syncthreads();
  }
  if (tid == 0) inv_s = (e_end > s) ? (1.0f / red[0]) : 0.f;
  __syncthreads();
  const float inv = inv_s;

  const int f = tid & 31;
  const int grp = tid >> 5;
  float acc = 0.f;
  for (int i = s + grp; i < e_end; i += 8)
    acc += __expf(gate[i] - m) * h[(size_t)i * 32 + f];
  red[tid] = acc;
  __syncthreads();
  if (tid < 32) {
    float a = 0.f;
#pragma unroll
    for (int j = 0; j < 8; ++j) a += red[j * 32 + tid];
    pooled_s[tid] = a * inv;
  }
  __syncthreads();

  if (tid < 9) {
    float o = bf_[tid];
#pragma unroll
    for (int kk = 0; kk < 32; ++kk) o += pooled_s[kk] * Wf[kk * 9 + tid];
    out[g * 9 + tid] = o;
  }
}

// ---------------------------------------------------------------------------
extern "C" void kernel_launch(void* const* d_in, const int* in_sizes, int n_in,
                              void* d_out, int out_size, void* d_ws, size_t ws_size,
                              hipStream_t stream) {
  const int N = in_sizes[2];       // 10000 nodes
  const int E = in_sizes[1] / 2;   // 160000 edges
  const int G = 16;

  const float* x = (const float*)d_in[0];
  const int* ei = (const int*)d_in[1];
  const int* batch = (const int*)d_in[2];
  const int* src = ei;
  const int* dst = ei + E;
  const float* Wg = (const float*)d_in[35];
  const float* bg = (const float*)d_in[36];
  const float* Wf = (const float*)d_in[37];
  const float* bf_ = (const float*)d_in[38];
  float* out = (float*)d_out;

  char* p = (char*)d_ws;
  auto carve = [&](size_t bytes) -> char* {
    char* r = p;
    p += (bytes + 255) & ~(size_t)255;
    return r;
  };
  int* deg = (int*)carve((size_t)N * 4);
  int* offs = (int*)carve((size_t)(N + 1) * 4);
  int* cursor = (int*)carve((size_t)N * 4);
  int* csr_src = (int*)carve((size_t)E * 4);
  int* csr_dst = (int*)carve((size_t)E * 4);
  float* logits = (float*)carve((size_t)E * 4);
  __bf16* Ab = (__bf16*)carve((size_t)N * 512 * 2);      // bf16 activations
  __bf16* Wt = (__bf16*)carve((size_t)512 * 2048 * 2);   // packed transposed weights
  float* bcat = (float*)carve(2048 * 4);
  float* qkvs = (float*)carve((size_t)N * 2048 * 4);     // fused gemm out [N,4*fout]
  float* ha = (float*)carve((size_t)N * 512 * 4);
  float* hb = (float*)carve((size_t)N * 512 * 4);
  float* gate = (float*)carve((size_t)N * 4);
  int* bounds = (int*)carve((size_t)(G + 1) * 4);
  (void)ws_size;

  // ---- CSR build ----
  hipMemsetAsync(deg, 0, (size_t)N * 4, stream);
  hipMemsetAsync(cursor, 0, (size_t)N * 4, stream);
  hist_kernel<<<(E + 255) / 256, 256, 0, stream>>>(dst, deg, E);
  scan_kernel<<<1, 1024, 0, stream>>>(deg, offs, N);
  scatter_kernel<<<(E + 255) / 256, 256, 0, stream>>>(src, dst, offs, cursor, csr_src, csr_dst, E);

  // ---- layers ----
  const int fins[4] = {128, 512, 256, 64};
  const int fouts[4] = {512, 256, 64, 32};
  const int bases[4] = {3, 11, 19, 27};
  const float* hin = x;
  float* houts[4] = {ha, hb, ha, hb};

  for (int l = 0; l < 4; ++l) {
    const int fin = fins[l], fout = fouts[l];
    const int Nc = 4 * fout;  // fused gemm width
    const float* Wq = (const float*)d_in[bases[l] + 0];
    const float* bq = (const float*)d_in[bases[l] + 1];
    const float* Wk = (const float*)d_in[bases[l] + 2];
    const float* bk = (const float*)d_in[bases[l] + 3];
    const float* Wv = (const float*)d_in[bases[l] + 4];
    const float* bv = (const float*)d_in[bases[l] + 5];
    const float* Ws = (const float*)d_in[bases[l] + 6];
    const float* bs = (const float*)d_in[bases[l] + 7];
    float* hout = houts[l];

    // cast activations to bf16
    int n4 = N * fin / 4;
    cast_bf16_kernel<<<(n4 + 255) / 256, 256, 0, stream>>>(hin, Ab, n4);
    // pack weights (transposed, bf16) + biases
    int ptot = Nc * fin;
    pack_w_kernel<<<(ptot + 255) / 256, 256, 0, stream>>>(
        Wq, Wk, Wv, Ws, bq, bk, bv, bs, Wt, bcat, fin, fout);
    // fused q|k|v|s GEMM: [N,fin] @ [fin,4fout] -> qkvs [N,4fout]
    dim3 grid(Nc / GBN, (N + GBM - 1) / GBM);
    gemm_mfma_kernel<<<grid, 256, 0, stream>>>(Ab, Wt, bcat, qkvs, N, fin, Nc);

    float scale = 1.0f / sqrtf((float)fout);
    edge_logit_kernel<<<((size_t)E * 16 + 255) / 256, 256, 0, stream>>>(
        qkvs, csr_src, csr_dst, logits, E, fout, Nc, scale);
    attn_agg_kernel<<<(N * 64 + 255) / 256, 256, 0, stream>>>(
        qkvs, csr_src, offs, logits, hout, N, fout, Nc);
    hin = hout;
  }

  // ---- pooling (atomic-free) ----
  gate_kernel<<<(N + 255) / 256, 256, 0, stream>>>(hin, Wg, bg, gate, N);
  bounds_kernel<<<1, G + 1, 0, stream>>>(batch, bounds, N, G);
  pool_final_kernel<<<G, 256, 0, stream>>>(hin, gate, bounds, Wf, bf_, out);
}

// Round 5
// 484.080 us; speedup vs baseline: 3.5888x; 1.0338x over previous
//
#include <hip/hip_runtime.h>
#include <hip/hip_bf16.h>
#include <math.h>

// ---------------------------------------------------------------------------
// TransformerNet: 4x TransformerConv (heads=1) + ELU, GlobalAttention pool,
// final linear.
// R1: edge-parallel logits + per-node softmax-agg.
// R2: atomic-free pooling (sorted batch -> binary-search bounds).
// R3: fused q|k|v|s bf16 MFMA GEMM per layer.
// R4: k/v/h stored bf16 (halves random-gather bytes: attn_agg was 35% HBM,
//     143MB fetch/dispatch); GEMM epilogue dual-stores fp32 q|skip + bf16 k|v;
//     cast kernels eliminated (h written bf16 directly); 2 waves/node for
//     d=512 aggregation for 2x memory-level parallelism.
// ---------------------------------------------------------------------------

typedef __bf16 bf16x8 __attribute__((ext_vector_type(8)));
typedef __bf16 bf16x4 __attribute__((ext_vector_type(4)));
typedef float f32x4 __attribute__((ext_vector_type(4)));

#define GBM 128
#define GBN 128
#define GBK 32
#define LDP 40  // LDS row stride in bf16 (20 words -> 2-way bank alias, free)

// Fused GEMM: [M,K](bf16) @ Wt[4f,K]^T -> q|skip fp32 qs[M][2f], k|v bf16 kvb[M][2f]
__global__ __launch_bounds__(256) void gemm_mfma_kernel(
    const __bf16* __restrict__ A, const __bf16* __restrict__ Bt,
    const float* __restrict__ bias, float* __restrict__ qs,
    __bf16* __restrict__ kvb, int M, int K, int fout, int fshift) {
  __shared__ __bf16 As[GBM * LDP];
  __shared__ __bf16 Bs[GBN * LDP];
  const int tid = threadIdx.x;
  const int wave = tid >> 6;
  const int lane = tid & 63;
  const int quad = lane >> 4;
  const int l16 = lane & 15;
  const int m0 = blockIdx.y * GBM;
  const int n0 = blockIdx.x * GBN;
  const int wm = (wave & 1) * 64;
  const int wn = (wave >> 1) * 64;
  const int fmask = fout - 1;
  const int ld2 = 2 * fout;

  f32x4 acc[4][4] = {};

  for (int k0 = 0; k0 < K; k0 += GBK) {
#pragma unroll
    for (int it = 0; it < 2; ++it) {
      int idx = tid + it * 256;
      int row = idx >> 2, seg = idx & 3;
      bf16x8 av = {};
      int gr = m0 + row;
      if (gr < M) av = *(const bf16x8*)(A + (size_t)gr * K + k0 + seg * 8);
      *(bf16x8*)(As + row * LDP + seg * 8) = av;
      bf16x8 bv = *(const bf16x8*)(Bt + (size_t)(n0 + row) * K + k0 + seg * 8);
      *(bf16x8*)(Bs + row * LDP + seg * 8) = bv;
    }
    __syncthreads();

    bf16x8 af[4], bfr[4];
#pragma unroll
    for (int i = 0; i < 4; ++i) {
      af[i]  = *(const bf16x8*)(As + (wm + i * 16 + l16) * LDP + quad * 8);
      bfr[i] = *(const bf16x8*)(Bs + (wn + i * 16 + l16) * LDP + quad * 8);
    }
#pragma unroll
    for (int mi = 0; mi < 4; ++mi)
#pragma unroll
      for (int ni = 0; ni < 4; ++ni)
        acc[mi][ni] = __builtin_amdgcn_mfma_f32_16x16x32_bf16(
            af[mi], bfr[ni], acc[mi][ni], 0, 0, 0);
    __syncthreads();
  }

  // C/D layout: col = lane&15, row = quad*4 + reg
#pragma unroll
  for (int mi = 0; mi < 4; ++mi) {
#pragma unroll
    for (int r = 0; r < 4; ++r) {
      int row = m0 + wm + mi * 16 + quad * 4 + r;
      if (row < M) {
        size_t rb = (size_t)row * ld2;
#pragma unroll
        for (int ni = 0; ni < 4; ++ni) {
          int col = n0 + wn + ni * 16 + l16;
          float val = acc[mi][ni][r] + bias[col];
          int blk = col >> fshift;
          int j = col & fmask;
          if (blk == 0)      qs[rb + j] = val;                    // q
          else if (blk == 1) kvb[rb + j] = (__bf16)val;           // k
          else if (blk == 2) kvb[rb + fout + j] = (__bf16)val;    // v
          else               qs[rb + fout + j] = val;             // skip
        }
      }
    }
  }
}

// pack 4 fp32 weight matrices [K,fout] -> transposed bf16 Wt[4*fout][K]; concat biases.
__global__ void pack_w_kernel(const float* __restrict__ Wq, const float* __restrict__ Wk,
                              const float* __restrict__ Wv, const float* __restrict__ Ws,
                              const float* __restrict__ bq, const float* __restrict__ bk,
                              const float* __restrict__ bv, const float* __restrict__ bs,
                              __bf16* __restrict__ Wt, float* __restrict__ bcat,
                              int K, int fout) {
  int total = 4 * fout * K;
  int tid = blockIdx.x * blockDim.x + threadIdx.x;
  if (tid < total) {
    int c = tid / K;
    int kk = tid - c * K;
    int blk = c / fout;
    int j = c - blk * fout;
    const float* W = blk == 0 ? Wq : blk == 1 ? Wk : blk == 2 ? Wv : Ws;
    Wt[tid] = (__bf16)W[(size_t)kk * fout + j];
  }
  if (tid < 4 * fout) {
    int blk = tid / fout, j = tid - blk * fout;
    const float* b = blk == 0 ? bq : blk == 1 ? bk : blk == 2 ? bv : bs;
    bcat[tid] = b[j];
  }
}

// fp32 -> bf16 cast (for the initial x only)
__global__ void cast_bf16_kernel(const float* __restrict__ in, __bf16* __restrict__ out,
                                 int n4) {
  int i = blockIdx.x * blockDim.x + threadIdx.x;
  if (i >= n4) return;
  float4 v = ((const float4*)in)[i];
  bf16x4 o;
  o[0] = (__bf16)v.x; o[1] = (__bf16)v.y; o[2] = (__bf16)v.z; o[3] = (__bf16)v.w;
  *(bf16x4*)(out + (size_t)i * 4) = o;
}

// ---------------- CSR build ----------------
__global__ void hist_kernel(const int* __restrict__ dst, int* __restrict__ deg, int E) {
  int e = blockIdx.x * blockDim.x + threadIdx.x;
  if (e < E) atomicAdd(&deg[dst[e]], 1);
}

__global__ __launch_bounds__(1024) void scan_kernel(const int* __restrict__ deg,
                                                    int* __restrict__ offs, int N) {
  __shared__ int sums[1024];
  const int tid = threadIdx.x;
  const int chunk = (N + 1023) / 1024;
  const int start = tid * chunk;
  int s = 0;
  for (int i = 0; i < chunk; ++i) {
    int idx = start + i;
    if (idx < N) s += deg[idx];
  }
  sums[tid] = s;
  __syncthreads();
  for (int off = 1; off < 1024; off <<= 1) {
    int t = (tid >= off) ? sums[tid - off] : 0;
    __syncthreads();
    sums[tid] += t;
    __syncthreads();
  }
  int run = (tid == 0) ? 0 : sums[tid - 1];
  for (int i = 0; i < chunk; ++i) {
    int idx = start + i;
    if (idx < N) {
      offs[idx] = run;
      run += deg[idx];
    }
  }
  if (tid == 1023) offs[N] = sums[1023];
}

__global__ void scatter_kernel(const int* __restrict__ src, const int* __restrict__ dst,
                               const int* __restrict__ offs, int* __restrict__ cursor,
                               int* __restrict__ csr_src, int* __restrict__ csr_dst, int E) {
  int e = blockIdx.x * blockDim.x + threadIdx.x;
  if (e >= E) return;
  int d = dst[e];
  int pos = offs[d] + atomicAdd(&cursor[d], 1);
  csr_src[pos] = src[e];
  csr_dst[pos] = d;
}

// ---------------- edge-parallel logits (16 lanes per edge) -----------------
// q fp32 at qs[.,0:d]; k bf16 at kvb[.,0:d]; row stride 2d both.
__global__ __launch_bounds__(256) void edge_logit_kernel(
    const float* __restrict__ qs, const __bf16* __restrict__ kvb,
    const int* __restrict__ csr_src, const int* __restrict__ csr_dst,
    float* __restrict__ logits, int E, int d, float scale) {
  const int g = (blockIdx.x * 256 + threadIdx.x) >> 4;
  const int l = threadIdx.x & 15;
  if (g >= E) return;
  const int ld2 = 2 * d;
  const int s = csr_src[g];
  const int dt = csr_dst[g];
  const float* qr = qs + (size_t)dt * ld2;
  const __bf16* kr = kvb + (size_t)s * ld2;
  const int n8 = d >> 3;
  float p = 0.f;
  for (int i = l; i < n8; i += 16) {
    bf16x8 kv = *(const bf16x8*)(kr + i * 8);
    const float4* q4 = (const float4*)(qr + i * 8);
    float4 qa = q4[0], qb = q4[1];
    p += qa.x * (float)kv[0] + qa.y * (float)kv[1] + qa.z * (float)kv[2] +
         qa.w * (float)kv[3] + qb.x * (float)kv[4] + qb.y * (float)kv[5] +
         qb.z * (float)kv[6] + qb.w * (float)kv[7];
  }
#pragma unroll
  for (int off = 8; off; off >>= 1) p += __shfl_xor(p, off);
  if (l == 0) logits[g] = p * scale;
}

// ---------------- per-node softmax + aggregate --------------------------
// 1<<sshift waves per node, each covering 256 features. v bf16 at kvb[.,d:2d],
// skip fp32 at qs[.,d:2d]. Writes h bf16 [N][d] = elu(agg + skip).
__global__ __launch_bounds__(256) void attn_agg_kernel(
    const float* __restrict__ qs, const __bf16* __restrict__ kvb,
    const int* __restrict__ csr_src, const int* __restrict__ offs,
    const float* __restrict__ logits, __bf16* __restrict__ h_out,
    int N, int d, int sshift) {
  const int W = (blockIdx.x * 256 + threadIdx.x) >> 6;
  const int lane = threadIdx.x & 63;
  const int node = W >> sshift;
  const int seg = W & ((1 << sshift) - 1);
  if (node >= N) return;
  const int ld2 = 2 * d;
  const int begin = offs[node];
  const int deg = offs[node + 1] - begin;

  float m = -INFINITY;
  for (int c = 0; c < deg; c += 64) {
    int i = c + lane;
    if (i < deg) m = fmaxf(m, logits[begin + i]);
  }
#pragma unroll
  for (int off = 32; off; off >>= 1) m = fmaxf(m, __shfl_xor(m, off));

  const int f = (seg << 8) + lane * 4;
  const bool act = f < d;
  float4 acc = make_float4(0.f, 0.f, 0.f, 0.f);
  float ssum = 0.f;
  const __bf16* vbase = kvb + d;

  for (int c = 0; c < deg; c += 64) {
    int i = c + lane;
    float w = 0.f;
    int s = 0;
    if (i < deg) {
      w = __expf(logits[begin + i] - m);
      s = csr_src[begin + i];
    }
    ssum += w;
    int cnt = min(64, deg - c);
    for (int e = 0; e < cnt; ++e) {
      float we = __shfl(w, e);
      int se = __shfl(s, e);
      if (act) {
        bf16x4 vv = *(const bf16x4*)(vbase + (size_t)se * ld2 + f);
        acc.x += we * (float)vv[0];
        acc.y += we * (float)vv[1];
        acc.z += we * (float)vv[2];
        acc.w += we * (float)vv[3];
      }
    }
  }
#pragma unroll
  for (int off = 32; off; off >>= 1) ssum += __shfl_xor(ssum, off);
  float inv = (deg > 0) ? (1.0f / ssum) : 0.f;

  if (act) {
    const float4 sk = *(const float4*)(qs + (size_t)node * ld2 + d + f);
    float rx = acc.x * inv + sk.x;
    float ry = acc.y * inv + sk.y;
    float rz = acc.z * inv + sk.z;
    float rw = acc.w * inv + sk.w;
    rx = (rx > 0.f) ? rx : expm1f(rx);
    ry = (ry > 0.f) ? ry : expm1f(ry);
    rz = (rz > 0.f) ? rz : expm1f(rz);
    rw = (rw > 0.f) ? rw : expm1f(rw);
    bf16x4 o;
    o[0] = (__bf16)rx; o[1] = (__bf16)ry; o[2] = (__bf16)rz; o[3] = (__bf16)rw;
    *(bf16x4*)(h_out + (size_t)node * d + f) = o;
  }
}

// ---------------- pooling (atomic-free, h in bf16) ----------------
__global__ void gate_kernel(const __bf16* __restrict__ h, const float* __restrict__ Wg,
                            const float* __restrict__ bg, float* __restrict__ gate, int N) {
  int n = blockIdx.x * blockDim.x + threadIdx.x;
  if (n >= N) return;
  const bf16x8* hn = (const bf16x8*)(h + (size_t)n * 32);
  float g = bg[0];
#pragma unroll
  for (int i = 0; i < 4; ++i) {
    bf16x8 a = hn[i];
#pragma unroll
    for (int j = 0; j < 8; ++j) g += (float)a[j] * Wg[i * 8 + j];
  }
  gate[n] = g;
}

__global__ void bounds_kernel(const int* __restrict__ batch, int* __restrict__ bounds,
                              int N, int G) {
  int g = threadIdx.x;
  if (g > G) return;
  int lo = 0, hi = N;
  while (lo < hi) {
    int mid = (lo + hi) >> 1;
    if (batch[mid] < g) lo = mid + 1;
    else hi = mid;
  }
  bounds[g] = lo;
}

__global__ __launch_bounds__(256) void pool_final_kernel(
    const __bf16* __restrict__ h, const float* __restrict__ gate,
    const int* __restrict__ bounds, const float* __restrict__ Wf,
    const float* __restrict__ bf_, float* __restrict__ out) {
  __shared__ float red[256];
  __shared__ float pooled_s[32];
  __shared__ float m_s, inv_s;
  const int g = blockIdx.x;
  const int tid = threadIdx.x;
  const int s = bounds[g];
  const int e_end = bounds[g + 1];

  float m = -INFINITY;
  for (int i = s + tid; i < e_end; i += 256) m = fmaxf(m, gate[i]);
  red[tid] = m;
  __syncthreads();
  for (int off = 128; off; off >>= 1) {
    if (tid < off) red[tid] = fmaxf(red[tid], red[tid + off]);
    __syncthreads();
  }
  if (tid == 0) m_s = red[0];
  __syncthreads();
  m = m_s;

  float ss = 0.f;
  for (int i = s + tid; i < e_end; i += 256) ss += __expf(gate[i] - m);
  red[tid] = ss;
  __syncthreads();
  for (int off = 128; off; off >>= 1) {
    if (tid < off) red[tid] += red[tid + off];
    __syncthreads();
  }
  if (tid == 0) inv_s = (e_end > s) ? (1.0f / red[0]) : 0.f;
  __syncthreads();
  const float inv = inv_s;

  const int f = tid & 31;
  const int grp = tid >> 5;
  float acc = 0.f;
  for (int i = s + grp; i < e_end; i += 8)
    acc += __expf(gate[i] - m) * (float)h[(size_t)i * 32 + f];
  red[tid] = acc;
  __syncthreads();
  if (tid < 32) {
    float a = 0.f;
#pragma unroll
    for (int j = 0; j < 8; ++j) a += red[j * 32 + tid];
    pooled_s[tid] = a * inv;
  }
  __syncthreads();

  if (tid < 9) {
    float o = bf_[tid];
#pragma unroll
    for (int kk = 0; kk < 32; ++kk) o += pooled_s[kk] * Wf[kk * 9 + tid];
    out[g * 9 + tid] = o;
  }
}

// ---------------------------------------------------------------------------
extern "C" void kernel_launch(void* const* d_in, const int* in_sizes, int n_in,
                              void* d_out, int out_size, void* d_ws, size_t ws_size,
                              hipStream_t stream) {
  const int N = in_sizes[2];       // 10000 nodes
  const int E = in_sizes[1] / 2;   // 160000 edges
  const int G = 16;

  const float* x = (const float*)d_in[0];
  const int* ei = (const int*)d_in[1];
  const int* batch = (const int*)d_in[2];
  const int* src = ei;
  const int* dst = ei + E;
  const float* Wg = (const float*)d_in[35];
  const float* bg = (const float*)d_in[36];
  const float* Wf = (const float*)d_in[37];
  const float* bf_ = (const float*)d_in[38];
  float* out = (float*)d_out;

  char* p = (char*)d_ws;
  auto carve = [&](size_t bytes) -> char* {
    char* r = p;
    p += (bytes + 255) & ~(size_t)255;
    return r;
  };
  int* deg = (int*)carve((size_t)N * 4);
  int* offs = (int*)carve((size_t)(N + 1) * 4);
  int* cursor = (int*)carve((size_t)N * 4);
  int* csr_src = (int*)carve((size_t)E * 4);
  int* csr_dst = (int*)carve((size_t)E * 4);
  float* logits = (float*)carve((size_t)E * 4);
  __bf16* Ab = (__bf16*)carve((size_t)N * 128 * 2);     // bf16 cast of x
  __bf16* Wt = (__bf16*)carve((size_t)512 * 2048 * 2);  // packed transposed weights
  float* bcat = (float*)carve(2048 * 4);
  float* qs = (float*)carve((size_t)N * 1024 * 4);      // q|skip fp32 [N][2f]
  __bf16* kvb = (__bf16*)carve((size_t)N * 1024 * 2);   // k|v bf16 [N][2f]
  __bf16* ha = (__bf16*)carve((size_t)N * 512 * 2);     // h bf16
  __bf16* hb = (__bf16*)carve((size_t)N * 512 * 2);
  float* gate = (float*)carve((size_t)N * 4);
  int* bounds = (int*)carve((size_t)(G + 1) * 4);
  (void)ws_size;

  // ---- CSR build ----
  hipMemsetAsync(deg, 0, (size_t)N * 4, stream);
  hipMemsetAsync(cursor, 0, (size_t)N * 4, stream);
  hist_kernel<<<(E + 255) / 256, 256, 0, stream>>>(dst, deg, E);
  scan_kernel<<<1, 1024, 0, stream>>>(deg, offs, N);
  scatter_kernel<<<(E + 255) / 256, 256, 0, stream>>>(src, dst, offs, cursor, csr_src, csr_dst, E);

  // cast x -> bf16 once
  cast_bf16_kernel<<<(N * 128 / 4 + 255) / 256, 256, 0, stream>>>(x, Ab, N * 128 / 4);

  // ---- layers ----
  const int fins[4] = {128, 512, 256, 64};
  const int fouts[4] = {512, 256, 64, 32};
  const int fshifts[4] = {9, 8, 6, 5};
  const int bases[4] = {3, 11, 19, 27};
  const __bf16* hin = Ab;
  __bf16* houts[4] = {ha, hb, ha, hb};

  for (int l = 0; l < 4; ++l) {
    const int fin = fins[l], fout = fouts[l];
    const int Nc = 4 * fout;
    const float* Wq = (const float*)d_in[bases[l] + 0];
    const float* bq = (const float*)d_in[bases[l] + 1];
    const float* Wk = (const float*)d_in[bases[l] + 2];
    const float* bk = (const float*)d_in[bases[l] + 3];
    const float* Wv = (const float*)d_in[bases[l] + 4];
    const float* bv = (const float*)d_in[bases[l] + 5];
    const float* Ws = (const float*)d_in[bases[l] + 6];
    const float* bs = (const float*)d_in[bases[l] + 7];
    __bf16* hout = houts[l];

    int ptot = Nc * fin;
    pack_w_kernel<<<(ptot + 255) / 256, 256, 0, stream>>>(
        Wq, Wk, Wv, Ws, bq, bk, bv, bs, Wt, bcat, fin, fout);

    dim3 grid(Nc / GBN, (N + GBM - 1) / GBM);
    gemm_mfma_kernel<<<grid, 256, 0, stream>>>(hin, Wt, bcat, qs, kvb, N, fin,
                                               fout, fshifts[l]);

    float scale = 1.0f / sqrtf((float)fout);
    edge_logit_kernel<<<((size_t)E * 16 + 255) / 256, 256, 0, stream>>>(
        qs, kvb, csr_src, csr_dst, logits, E, fout, scale);

    int sshift = (fout > 256) ? 1 : 0;
    size_t waves = (size_t)N << sshift;
    attn_agg_kernel<<<(waves * 64 + 255) / 256, 256, 0, stream>>>(
        qs, kvb, csr_src, offs, logits, hout, N, fout, sshift);
    hin = hout;
  }

  // ---- pooling ----
  gate_kernel<<<(N + 255) / 256, 256, 0, stream>>>(hin, Wg, bg, gate, N);
  bounds_kernel<<<1, G + 1, 0, stream>>>(batch, bounds, N, G);
  pool_final_kernel<<<G, 256, 0, stream>>>(hin, gate, bounds, Wf, bf_, out);
}

// Round 6
// 408.805 us; speedup vs baseline: 4.2496x; 1.1841x over previous
//
#include <hip/hip_runtime.h>
#include <hip/hip_bf16.h>
#include <math.h>

// ---------------------------------------------------------------------------
// TransformerNet: 4x TransformerConv (heads=1) + ELU, GlobalAttention pool,
// final linear.
// R1: edge-parallel logits + per-node softmax-agg.
// R2: atomic-free pooling (sorted batch -> binary-search bounds).
// R3: fused q|k|v|s bf16 MFMA GEMM per layer.
// R4: k/v/h bf16.
// R5: GEMM fixed per counters (MfmaUtil 4%, 1.29M LDS conflicts, 60MB writes):
//     LDS row stride 68 bf16 (34 words -> bank permutation, 2-way max);
//     GBK 32->64 (half the barriers); all-bf16 qkvs[N][4f] output
//     (branch-free epilogue, writes/4, q-gather bytes/2); packs merged.
// ---------------------------------------------------------------------------

typedef __bf16 bf16x8 __attribute__((ext_vector_type(8)));
typedef __bf16 bf16x4 __attribute__((ext_vector_type(4)));
typedef float f32x4 __attribute__((ext_vector_type(4)));

#define GBM 128
#define GBN 128
#define GBK 64
#define LDR 68  // LDS row stride in bf16: 34 words -> (34*l)%32 permutation

// Fused GEMM: A[M,K](bf16) @ Wt[Nc,K]^T + bias -> qkvs[M][Nc] (bf16)
__global__ __launch_bounds__(256) void gemm_mfma_kernel(
    const __bf16* __restrict__ A, const __bf16* __restrict__ Bt,
    const float* __restrict__ bias, __bf16* __restrict__ qkvs,
    int M, int K, int Nc) {
  __shared__ __bf16 As[GBM * LDR];
  __shared__ __bf16 Bs[GBN * LDR];
  const int tid = threadIdx.x;
  const int wave = tid >> 6;
  const int lane = tid & 63;
  const int quad = lane >> 4;
  const int l16 = lane & 15;
  const int m0 = blockIdx.y * GBM;
  const int n0 = blockIdx.x * GBN;
  const int wm = (wave & 1) * 64;
  const int wn = (wave >> 1) * 64;

  f32x4 acc[4][4] = {};

  const int srow = tid >> 3;        // 0..31
  const int sseg = (tid & 7) * 8;   // 0..56

  for (int k0 = 0; k0 < K; k0 += GBK) {
    // stage 128x64 A and B tiles: 1024 bf16x8 chunks, 4 iters of 256 threads
#pragma unroll
    for (int it = 0; it < 4; ++it) {
      int row = srow + it * 32;
      bf16x8 av = {};
      int gr = m0 + row;
      if (gr < M) av = *(const bf16x8*)(A + (size_t)gr * K + k0 + sseg);
      *(bf16x8*)(As + row * LDR + sseg) = av;
      bf16x8 bv = *(const bf16x8*)(Bt + (size_t)(n0 + row) * K + k0 + sseg);
      *(bf16x8*)(Bs + row * LDR + sseg) = bv;
    }
    __syncthreads();

#pragma unroll
    for (int ks = 0; ks < 2; ++ks) {
      bf16x8 af[4], bfr[4];
#pragma unroll
      for (int i = 0; i < 4; ++i) {
        af[i]  = *(const bf16x8*)(As + (wm + i * 16 + l16) * LDR + ks * 32 + quad * 8);
        bfr[i] = *(const bf16x8*)(Bs + (wn + i * 16 + l16) * LDR + ks * 32 + quad * 8);
      }
#pragma unroll
      for (int mi = 0; mi < 4; ++mi)
#pragma unroll
        for (int ni = 0; ni < 4; ++ni)
          acc[mi][ni] = __builtin_amdgcn_mfma_f32_16x16x32_bf16(
              af[mi], bfr[ni], acc[mi][ni], 0, 0, 0);
    }
    __syncthreads();
  }

  // C/D layout: col = lane&15, row = quad*4 + reg. Branch-free bf16 store.
  float bsv[4];
#pragma unroll
  for (int ni = 0; ni < 4; ++ni) bsv[ni] = bias[n0 + wn + ni * 16 + l16];
#pragma unroll
  for (int mi = 0; mi < 4; ++mi) {
#pragma unroll
    for (int r = 0; r < 4; ++r) {
      int row = m0 + wm + mi * 16 + quad * 4 + r;
      if (row < M) {
        size_t rb = (size_t)row * Nc;
#pragma unroll
        for (int ni = 0; ni < 4; ++ni) {
          int col = n0 + wn + ni * 16 + l16;
          qkvs[rb + col] = (__bf16)(acc[mi][ni][r] + bsv[ni]);
        }
      }
    }
  }
}

// ---- pack ALL layers' weights -> transposed bf16 + concat fp32 biases ----
// Layer l: Wt_l[4*fout][fin] at woff; dims are powers of two (shift decode).
__global__ void pack_all_kernel(
    const float* W0q, const float* W0k, const float* W0v, const float* W0s,
    const float* b0q, const float* b0k, const float* b0v, const float* b0s,
    const float* W1q, const float* W1k, const float* W1v, const float* W1s,
    const float* b1q, const float* b1k, const float* b1v, const float* b1s,
    const float* W2q, const float* W2k, const float* W2v, const float* W2s,
    const float* b2q, const float* b2k, const float* b2v, const float* b2s,
    const float* W3q, const float* W3k, const float* W3v, const float* W3s,
    const float* b3q, const float* b3k, const float* b3v, const float* b3s,
    __bf16* __restrict__ Wt, float* __restrict__ bcat) {
  const int t = blockIdx.x * 256 + threadIdx.x;
  // weight totals: L0 2048*128=262144, L1 1024*512=524288 (->786432),
  // L2 256*256=65536 (->851968), L3 128*64=8192 (->860160). bias: +3456.
  if (t < 860160) {
    int l, local, ksh, fsh;
    if (t < 262144)      { l = 0; local = t;          ksh = 7; fsh = 9; }
    else if (t < 786432) { l = 1; local = t - 262144; ksh = 9; fsh = 8; }
    else if (t < 851968) { l = 2; local = t - 786432; ksh = 8; fsh = 6; }
    else                 { l = 3; local = t - 851968; ksh = 6; fsh = 5; }
    const int K = 1 << ksh, fout = 1 << fsh;
    int c = local >> ksh;
    int kk = local & (K - 1);
    int blk = c >> fsh;
    int j = c & (fout - 1);
    const float* W;
    if (l == 0)      W = blk == 0 ? W0q : blk == 1 ? W0k : blk == 2 ? W0v : W0s;
    else if (l == 1) W = blk == 0 ? W1q : blk == 1 ? W1k : blk == 2 ? W1v : W1s;
    else if (l == 2) W = blk == 0 ? W2q : blk == 1 ? W2k : blk == 2 ? W2v : W2s;
    else             W = blk == 0 ? W3q : blk == 1 ? W3k : blk == 2 ? W3v : W3s;
    Wt[t] = (__bf16)W[((size_t)kk << fsh) + j];
  } else if (t < 860160 + 3456) {
    int u = t - 860160;
    int l, local, fsh, boff;
    if (u < 2048)      { l = 0; local = u;        fsh = 9; boff = 0; }
    else if (u < 3072) { l = 1; local = u - 2048; fsh = 8; boff = 2048; }
    else if (u < 3328) { l = 2; local = u - 3072; fsh = 6; boff = 3072; }
    else               { l = 3; local = u - 3328; fsh = 5; boff = 3328; }
    const int fout = 1 << fsh;
    int blk = local >> fsh, j = local & (fout - 1);
    const float* b;
    if (l == 0)      b = blk == 0 ? b0q : blk == 1 ? b0k : blk == 2 ? b0v : b0s;
    else if (l == 1) b = blk == 0 ? b1q : blk == 1 ? b1k : blk == 2 ? b1v : b1s;
    else if (l == 2) b = blk == 0 ? b2q : blk == 1 ? b2k : blk == 2 ? b2v : b2s;
    else             b = blk == 0 ? b3q : blk == 1 ? b3k : blk == 2 ? b3v : b3s;
    bcat[boff + local] = b[j];
  }
}

// fp32 -> bf16 cast (for the initial x only)
__global__ void cast_bf16_kernel(const float* __restrict__ in, __bf16* __restrict__ out,
                                 int n4) {
  int i = blockIdx.x * blockDim.x + threadIdx.x;
  if (i >= n4) return;
  float4 v = ((const float4*)in)[i];
  bf16x4 o;
  o[0] = (__bf16)v.x; o[1] = (__bf16)v.y; o[2] = (__bf16)v.z; o[3] = (__bf16)v.w;
  *(bf16x4*)(out + (size_t)i * 4) = o;
}

// ---------------- CSR build ----------------
__global__ void hist_kernel(const int* __restrict__ dst, int* __restrict__ deg, int E) {
  int e = blockIdx.x * blockDim.x + threadIdx.x;
  if (e < E) atomicAdd(&deg[dst[e]], 1);
}

__global__ __launch_bounds__(1024) void scan_kernel(const int* __restrict__ deg,
                                                    int* __restrict__ offs, int N) {
  __shared__ int sums[1024];
  const int tid = threadIdx.x;
  const int chunk = (N + 1023) / 1024;
  const int start = tid * chunk;
  int s = 0;
  for (int i = 0; i < chunk; ++i) {
    int idx = start + i;
    if (idx < N) s += deg[idx];
  }
  sums[tid] = s;
  __syncthreads();
  for (int off = 1; off < 1024; off <<= 1) {
    int t = (tid >= off) ? sums[tid - off] : 0;
    __syncthreads();
    sums[tid] += t;
    __syncthreads();
  }
  int run = (tid == 0) ? 0 : sums[tid - 1];
  for (int i = 0; i < chunk; ++i) {
    int idx = start + i;
    if (idx < N) {
      offs[idx] = run;
      run += deg[idx];
    }
  }
  if (tid == 1023) offs[N] = sums[1023];
}

__global__ void scatter_kernel(const int* __restrict__ src, const int* __restrict__ dst,
                               const int* __restrict__ offs, int* __restrict__ cursor,
                               int* __restrict__ csr_src, int* __restrict__ csr_dst, int E) {
  int e = blockIdx.x * blockDim.x + threadIdx.x;
  if (e >= E) return;
  int d = dst[e];
  int pos = offs[d] + atomicAdd(&cursor[d], 1);
  csr_src[pos] = src[e];
  csr_dst[pos] = d;
}

// ---------------- edge-parallel logits (16 lanes per edge) -----------------
// q bf16 at qkvs[.,0:d], k bf16 at qkvs[.,d:2d]; row stride 4d.
__global__ __launch_bounds__(256) void edge_logit_kernel(
    const __bf16* __restrict__ qkvs, const int* __restrict__ csr_src,
    const int* __restrict__ csr_dst, float* __restrict__ logits,
    int E, int d, float scale) {
  const int g = (blockIdx.x * 256 + threadIdx.x) >> 4;
  const int l = threadIdx.x & 15;
  if (g >= E) return;
  const int ld = 4 * d;
  const int s = csr_src[g];
  const int dt = csr_dst[g];
  const __bf16* qr = qkvs + (size_t)dt * ld;
  const __bf16* kr = qkvs + (size_t)s * ld + d;
  const int n8 = d >> 3;
  float p = 0.f;
  for (int i = l; i < n8; i += 16) {
    bf16x8 qv = *(const bf16x8*)(qr + i * 8);
    bf16x8 kv = *(const bf16x8*)(kr + i * 8);
#pragma unroll
    for (int j = 0; j < 8; ++j) p += (float)qv[j] * (float)kv[j];
  }
#pragma unroll
  for (int off = 8; off; off >>= 1) p += __shfl_xor(p, off);
  if (l == 0) logits[g] = p * scale;
}

// ---------------- per-node softmax + aggregate --------------------------
// 1<<sshift waves per node, 256 feats each. v at qkvs[.,2d:3d], skip at
// qkvs[.,3d:4d] (both bf16). Writes h bf16 [N][d] = elu(agg + skip).
__global__ __launch_bounds__(256) void attn_agg_kernel(
    const __bf16* __restrict__ qkvs, const int* __restrict__ csr_src,
    const int* __restrict__ offs, const float* __restrict__ logits,
    __bf16* __restrict__ h_out, int N, int d, int sshift) {
  const int W = (blockIdx.x * 256 + threadIdx.x) >> 6;
  const int lane = threadIdx.x & 63;
  const int node = W >> sshift;
  const int seg = W & ((1 << sshift) - 1);
  if (node >= N) return;
  const int ld = 4 * d;
  const int begin = offs[node];
  const int deg = offs[node + 1] - begin;

  float m = -INFINITY;
  for (int c = 0; c < deg; c += 64) {
    int i = c + lane;
    if (i < deg) m = fmaxf(m, logits[begin + i]);
  }
#pragma unroll
  for (int off = 32; off; off >>= 1) m = fmaxf(m, __shfl_xor(m, off));

  const int f = (seg << 8) + lane * 4;
  const bool act = f < d;
  float4 acc = make_float4(0.f, 0.f, 0.f, 0.f);
  float ssum = 0.f;
  const __bf16* vbase = qkvs + 2 * (size_t)d;

  for (int c = 0; c < deg; c += 64) {
    int i = c + lane;
    float w = 0.f;
    int s = 0;
    if (i < deg) {
      w = __expf(logits[begin + i] - m);
      s = csr_src[begin + i];
    }
    ssum += w;
    int cnt = min(64, deg - c);
    for (int e = 0; e < cnt; ++e) {
      float we = __shfl(w, e);
      int se = __shfl(s, e);
      if (act) {
        bf16x4 vv = *(const bf16x4*)(vbase + (size_t)se * ld + f);
        acc.x += we * (float)vv[0];
        acc.y += we * (float)vv[1];
        acc.z += we * (float)vv[2];
        acc.w += we * (float)vv[3];
      }
    }
  }
#pragma unroll
  for (int off = 32; off; off >>= 1) ssum += __shfl_xor(ssum, off);
  float inv = (deg > 0) ? (1.0f / ssum) : 0.f;

  if (act) {
    bf16x4 sk = *(const bf16x4*)(qkvs + (size_t)node * ld + 3 * d + f);
    float rx = acc.x * inv + (float)sk[0];
    float ry = acc.y * inv + (float)sk[1];
    float rz = acc.z * inv + (float)sk[2];
    float rw = acc.w * inv + (float)sk[3];
    rx = (rx > 0.f) ? rx : expm1f(rx);
    ry = (ry > 0.f) ? ry : expm1f(ry);
    rz = (rz > 0.f) ? rz : expm1f(rz);
    rw = (rw > 0.f) ? rw : expm1f(rw);
    bf16x4 o;
    o[0] = (__bf16)rx; o[1] = (__bf16)ry; o[2] = (__bf16)rz; o[3] = (__bf16)rw;
    *(bf16x4*)(h_out + (size_t)node * d + f) = o;
  }
}

// ---------------- pooling (atomic-free, h in bf16) ----------------
__global__ void gate_kernel(const __bf16* __restrict__ h, const float* __restrict__ Wg,
                            const float* __restrict__ bg, float* __restrict__ gate, int N) {
  int n = blockIdx.x * blockDim.x + threadIdx.x;
  if (n >= N) return;
  const bf16x8* hn = (const bf16x8*)(h + (size_t)n * 32);
  float g = bg[0];
#pragma unroll
  for (int i = 0; i < 4; ++i) {
    bf16x8 a = hn[i];
#pragma unroll
    for (int j = 0; j < 8; ++j) g += (float)a[j] * Wg[i * 8 + j];
  }
  gate[n] = g;
}

__global__ void bounds_kernel(const int* __restrict__ batch, int* __restrict__ bounds,
                              int N, int G) {
  int g = threadIdx.x;
  if (g > G) return;
  int lo = 0, hi = N;
  while (lo < hi) {
    int mid = (lo + hi) >> 1;
    if (batch[mid] < g) lo = mid + 1;
    else hi = mid;
  }
  bounds[g] = lo;
}

__global__ __launch_bounds__(256) void pool_final_kernel(
    const __bf16* __restrict__ h, const float* __restrict__ gate,
    const int* __restrict__ bounds, const float* __restrict__ Wf,
    const float* __restrict__ bf_, float* __restrict__ out) {
  __shared__ float red[256];
  __shared__ float pooled_s[32];
  __shared__ float m_s, inv_s;
  const int g = blockIdx.x;
  const int tid = threadIdx.x;
  const int s = bounds[g];
  const int e_end = bounds[g + 1];

  float m = -INFINITY;
  for (int i = s + tid; i < e_end; i += 256) m = fmaxf(m, gate[i]);
  red[tid] = m;
  __syncthreads();
  for (int off = 128; off; off >>= 1) {
    if (tid < off) red[tid] = fmaxf(red[tid], red[tid + off]);
    __syncthreads();
  }
  if (tid == 0) m_s = red[0];
  __syncthreads();
  m = m_s;

  float ss = 0.f;
  for (int i = s + tid; i < e_end; i += 256) ss += __expf(gate[i] - m);
  red[tid] = ss;
  __syncthreads();
  for (int off = 128; off; off >>= 1) {
    if (tid < off) red[tid] += red[tid + off];
    __syncthreads();
  }
  if (tid == 0) inv_s = (e_end > s) ? (1.0f / red[0]) : 0.f;
  __syncthreads();
  const float inv = inv_s;

  const int f = tid & 31;
  const int grp = tid >> 5;
  float acc = 0.f;
  for (int i = s + grp; i < e_end; i += 8)
    acc += __expf(gate[i] - m) * (float)h[(size_t)i * 32 + f];
  red[tid] = acc;
  __syncthreads();
  if (tid < 32) {
    float a = 0.f;
#pragma unroll
    for (int j = 0; j < 8; ++j) a += red[j * 32 + tid];
    pooled_s[tid] = a * inv;
  }
  __syncthreads();

  if (tid < 9) {
    float o = bf_[tid];
#pragma unroll
    for (int kk = 0; kk < 32; ++kk) o += pooled_s[kk] * Wf[kk * 9 + tid];
    out[g * 9 + tid] = o;
  }
}

// ---------------------------------------------------------------------------
extern "C" void kernel_launch(void* const* d_in, const int* in_sizes, int n_in,
                              void* d_out, int out_size, void* d_ws, size_t ws_size,
                              hipStream_t stream) {
  const int N = in_sizes[2];       // 10000 nodes
  const int E = in_sizes[1] / 2;   // 160000 edges
  const int G = 16;

  const float* x = (const float*)d_in[0];
  const int* ei = (const int*)d_in[1];
  const int* batch = (const int*)d_in[2];
  const int* src = ei;
  const int* dst = ei + E;
  const float* Wg = (const float*)d_in[35];
  const float* bg = (const float*)d_in[36];
  const float* Wf = (const float*)d_in[37];
  const float* bf_ = (const float*)d_in[38];
  float* out = (float*)d_out;

  char* p = (char*)d_ws;
  auto carve = [&](size_t bytes) -> char* {
    char* r = p;
    p += (bytes + 255) & ~(size_t)255;
    return r;
  };
  int* deg = (int*)carve((size_t)N * 4);
  int* offs = (int*)carve((size_t)(N + 1) * 4);
  int* cursor = (int*)carve((size_t)N * 4);
  int* csr_src = (int*)carve((size_t)E * 4);
  int* csr_dst = (int*)carve((size_t)E * 4);
  float* logits = (float*)carve((size_t)E * 4);
  __bf16* Ab = (__bf16*)carve((size_t)N * 128 * 2);     // bf16 cast of x
  __bf16* Wt = (__bf16*)carve((size_t)860160 * 2);      // all packed weights
  float* bcat = (float*)carve(3456 * 4);                // all biases
  __bf16* qkvs = (__bf16*)carve((size_t)N * 2048 * 2);  // q|k|v|s bf16 [N][4f]
  __bf16* ha = (__bf16*)carve((size_t)N * 512 * 2);     // h bf16
  __bf16* hb = (__bf16*)carve((size_t)N * 512 * 2);
  float* gate = (float*)carve((size_t)N * 4);
  int* bounds = (int*)carve((size_t)(G + 1) * 4);
  (void)ws_size;

  // ---- CSR build ----
  hipMemsetAsync(deg, 0, (size_t)N * 4, stream);
  hipMemsetAsync(cursor, 0, (size_t)N * 4, stream);
  hist_kernel<<<(E + 255) / 256, 256, 0, stream>>>(dst, deg, E);
  scan_kernel<<<1, 1024, 0, stream>>>(deg, offs, N);
  scatter_kernel<<<(E + 255) / 256, 256, 0, stream>>>(src, dst, offs, cursor, csr_src, csr_dst, E);

  // cast x -> bf16; pack all weights in one kernel
  cast_bf16_kernel<<<(N * 128 / 4 + 255) / 256, 256, 0, stream>>>(x, Ab, N * 128 / 4);
  const float** di = (const float**)d_in;
  pack_all_kernel<<<(860160 + 3456 + 255) / 256, 256, 0, stream>>>(
      di[3], di[5], di[7], di[9], di[4], di[6], di[8], di[10],
      di[11], di[13], di[15], di[17], di[12], di[14], di[16], di[18],
      di[19], di[21], di[23], di[25], di[20], di[22], di[24], di[26],
      di[27], di[29], di[31], di[33], di[28], di[30], di[32], di[34],
      Wt, bcat);

  // ---- layers ----
  const int fins[4] = {128, 512, 256, 64};
  const int fouts[4] = {512, 256, 64, 32};
  const size_t woffs[4] = {0, 262144, 786432, 851968};
  const int boffs[4] = {0, 2048, 3072, 3328};
  const __bf16* hin = Ab;
  __bf16* houts[4] = {ha, hb, ha, hb};

  for (int l = 0; l < 4; ++l) {
    const int fin = fins[l], fout = fouts[l];
    const int Nc = 4 * fout;
    __bf16* hout = houts[l];

    dim3 grid(Nc / GBN, (N + GBM - 1) / GBM);
    gemm_mfma_kernel<<<grid, 256, 0, stream>>>(hin, Wt + woffs[l], bcat + boffs[l],
                                               qkvs, N, fin, Nc);

    float scale = 1.0f / sqrtf((float)fout);
    edge_logit_kernel<<<((size_t)E * 16 + 255) / 256, 256, 0, stream>>>(
        qkvs, csr_src, csr_dst, logits, E, fout, scale);

    int sshift = (fout > 256) ? 1 : 0;
    size_t waves = (size_t)N << sshift;
    attn_agg_kernel<<<(waves * 64 + 255) / 256, 256, 0, stream>>>(
        qkvs, csr_src, offs, logits, hout, N, fout, sshift);
    hin = hout;
  }

  // ---- pooling ----
  gate_kernel<<<(N + 255) / 256, 256, 0, stream>>>(hin, Wg, bg, gate, N);
  bounds_kernel<<<1, G + 1, 0, stream>>>(batch, bounds, N, G);
  pool_final_kernel<<<G, 256, 0, stream>>>(hin, gate, bounds, Wf, bf_, out);
}

// Round 7
// 383.792 us; speedup vs baseline: 4.5265x; 1.0652x over previous
//
#include <hip/hip_runtime.h>
#include <hip/hip_bf16.h>
#include <math.h>

// ---------------------------------------------------------------------------
// TransformerNet: 4x TransformerConv (heads=1) + ELU, GlobalAttention pool,
// final linear.
// R1: edge-parallel logits + per-node softmax-agg.
// R2: atomic-free pooling (sorted batch -> binary-search bounds).
// R3: fused q|k|v|s bf16 MFMA GEMM per layer.
// R4: k/v/h bf16.  R5: GEMM LDS stride 68 / GBK 64 / all-bf16 qkvs.
// R6: attn_agg regrouped — ng groups/wave each own a different edge
//     (independent gather streams, 16B/lane, no shuffle in the loop; butterfly
//     combine at the end). edge_logit gets adaptive lanes/edge for small d.
//     Was latency-bound: HBM 35%, VALUBusy 12% (R4 counters).
// ---------------------------------------------------------------------------

typedef __bf16 bf16x8 __attribute__((ext_vector_type(8)));
typedef __bf16 bf16x4 __attribute__((ext_vector_type(4)));
typedef float f32x4 __attribute__((ext_vector_type(4)));

#define GBM 128
#define GBN 128
#define GBK 64
#define LDR 68  // LDS row stride in bf16: 34 words -> (34*l)%32 permutation

// Fused GEMM: A[M,K](bf16) @ Wt[Nc,K]^T + bias -> qkvs[M][Nc] (bf16)
__global__ __launch_bounds__(256) void gemm_mfma_kernel(
    const __bf16* __restrict__ A, const __bf16* __restrict__ Bt,
    const float* __restrict__ bias, __bf16* __restrict__ qkvs,
    int M, int K, int Nc) {
  __shared__ __bf16 As[GBM * LDR];
  __shared__ __bf16 Bs[GBN * LDR];
  const int tid = threadIdx.x;
  const int wave = tid >> 6;
  const int lane = tid & 63;
  const int quad = lane >> 4;
  const int l16 = lane & 15;
  const int m0 = blockIdx.y * GBM;
  const int n0 = blockIdx.x * GBN;
  const int wm = (wave & 1) * 64;
  const int wn = (wave >> 1) * 64;

  f32x4 acc[4][4] = {};

  const int srow = tid >> 3;
  const int sseg = (tid & 7) * 8;

  for (int k0 = 0; k0 < K; k0 += GBK) {
#pragma unroll
    for (int it = 0; it < 4; ++it) {
      int row = srow + it * 32;
      bf16x8 av = {};
      int gr = m0 + row;
      if (gr < M) av = *(const bf16x8*)(A + (size_t)gr * K + k0 + sseg);
      *(bf16x8*)(As + row * LDR + sseg) = av;
      bf16x8 bv = *(const bf16x8*)(Bt + (size_t)(n0 + row) * K + k0 + sseg);
      *(bf16x8*)(Bs + row * LDR + sseg) = bv;
    }
    __syncthreads();

#pragma unroll
    for (int ks = 0; ks < 2; ++ks) {
      bf16x8 af[4], bfr[4];
#pragma unroll
      for (int i = 0; i < 4; ++i) {
        af[i]  = *(const bf16x8*)(As + (wm + i * 16 + l16) * LDR + ks * 32 + quad * 8);
        bfr[i] = *(const bf16x8*)(Bs + (wn + i * 16 + l16) * LDR + ks * 32 + quad * 8);
      }
#pragma unroll
      for (int mi = 0; mi < 4; ++mi)
#pragma unroll
        for (int ni = 0; ni < 4; ++ni)
          acc[mi][ni] = __builtin_amdgcn_mfma_f32_16x16x32_bf16(
              af[mi], bfr[ni], acc[mi][ni], 0, 0, 0);
    }
    __syncthreads();
  }

  float bsv[4];
#pragma unroll
  for (int ni = 0; ni < 4; ++ni) bsv[ni] = bias[n0 + wn + ni * 16 + l16];
#pragma unroll
  for (int mi = 0; mi < 4; ++mi) {
#pragma unroll
    for (int r = 0; r < 4; ++r) {
      int row = m0 + wm + mi * 16 + quad * 4 + r;
      if (row < M) {
        size_t rb = (size_t)row * Nc;
#pragma unroll
        for (int ni = 0; ni < 4; ++ni) {
          int col = n0 + wn + ni * 16 + l16;
          qkvs[rb + col] = (__bf16)(acc[mi][ni][r] + bsv[ni]);
        }
      }
    }
  }
}

// ---- pack ALL layers' weights -> transposed bf16 + concat fp32 biases ----
__global__ void pack_all_kernel(
    const float* W0q, const float* W0k, const float* W0v, const float* W0s,
    const float* b0q, const float* b0k, const float* b0v, const float* b0s,
    const float* W1q, const float* W1k, const float* W1v, const float* W1s,
    const float* b1q, const float* b1k, const float* b1v, const float* b1s,
    const float* W2q, const float* W2k, const float* W2v, const float* W2s,
    const float* b2q, const float* b2k, const float* b2v, const float* b2s,
    const float* W3q, const float* W3k, const float* W3v, const float* W3s,
    const float* b3q, const float* b3k, const float* b3v, const float* b3s,
    __bf16* __restrict__ Wt, float* __restrict__ bcat) {
  const int t = blockIdx.x * 256 + threadIdx.x;
  if (t < 860160) {
    int l, local, ksh, fsh;
    if (t < 262144)      { l = 0; local = t;          ksh = 7; fsh = 9; }
    else if (t < 786432) { l = 1; local = t - 262144; ksh = 9; fsh = 8; }
    else if (t < 851968) { l = 2; local = t - 786432; ksh = 8; fsh = 6; }
    else                 { l = 3; local = t - 851968; ksh = 6; fsh = 5; }
    const int K = 1 << ksh, fout = 1 << fsh;
    int c = local >> ksh;
    int kk = local & (K - 1);
    int blk = c >> fsh;
    int j = c & (fout - 1);
    const float* W;
    if (l == 0)      W = blk == 0 ? W0q : blk == 1 ? W0k : blk == 2 ? W0v : W0s;
    else if (l == 1) W = blk == 0 ? W1q : blk == 1 ? W1k : blk == 2 ? W1v : W1s;
    else if (l == 2) W = blk == 0 ? W2q : blk == 1 ? W2k : blk == 2 ? W2v : W2s;
    else             W = blk == 0 ? W3q : blk == 1 ? W3k : blk == 2 ? W3v : W3s;
    Wt[t] = (__bf16)W[((size_t)kk << fsh) + j];
  } else if (t < 860160 + 3456) {
    int u = t - 860160;
    int l, local, fsh, boff;
    if (u < 2048)      { l = 0; local = u;        fsh = 9; boff = 0; }
    else if (u < 3072) { l = 1; local = u - 2048; fsh = 8; boff = 2048; }
    else if (u < 3328) { l = 2; local = u - 3072; fsh = 6; boff = 3072; }
    else               { l = 3; local = u - 3328; fsh = 5; boff = 3328; }
    const int fout = 1 << fsh;
    int blk = local >> fsh, j = local & (fout - 1);
    const float* b;
    if (l == 0)      b = blk == 0 ? b0q : blk == 1 ? b0k : blk == 2 ? b0v : b0s;
    else if (l == 1) b = blk == 0 ? b1q : blk == 1 ? b1k : blk == 2 ? b1v : b1s;
    else if (l == 2) b = blk == 0 ? b2q : blk == 1 ? b2k : blk == 2 ? b2v : b2s;
    else             b = blk == 0 ? b3q : blk == 1 ? b3k : blk == 2 ? b3v : b3s;
    bcat[boff + local] = b[j];
  }
}

__global__ void cast_bf16_kernel(const float* __restrict__ in, __bf16* __restrict__ out,
                                 int n4) {
  int i = blockIdx.x * blockDim.x + threadIdx.x;
  if (i >= n4) return;
  float4 v = ((const float4*)in)[i];
  bf16x4 o;
  o[0] = (__bf16)v.x; o[1] = (__bf16)v.y; o[2] = (__bf16)v.z; o[3] = (__bf16)v.w;
  *(bf16x4*)(out + (size_t)i * 4) = o;
}

// ---------------- CSR build ----------------
__global__ void hist_kernel(const int* __restrict__ dst, int* __restrict__ deg, int E) {
  int e = blockIdx.x * blockDim.x + threadIdx.x;
  if (e < E) atomicAdd(&deg[dst[e]], 1);
}

__global__ __launch_bounds__(1024) void scan_kernel(const int* __restrict__ deg,
                                                    int* __restrict__ offs, int N) {
  __shared__ int sums[1024];
  const int tid = threadIdx.x;
  const int chunk = (N + 1023) / 1024;
  const int start = tid * chunk;
  int s = 0;
  for (int i = 0; i < chunk; ++i) {
    int idx = start + i;
    if (idx < N) s += deg[idx];
  }
  sums[tid] = s;
  __syncthreads();
  for (int off = 1; off < 1024; off <<= 1) {
    int t = (tid >= off) ? sums[tid - off] : 0;
    __syncthreads();
    sums[tid] += t;
    __syncthreads();
  }
  int run = (tid == 0) ? 0 : sums[tid - 1];
  for (int i = 0; i < chunk; ++i) {
    int idx = start + i;
    if (idx < N) {
      offs[idx] = run;
      run += deg[idx];
    }
  }
  if (tid == 1023) offs[N] = sums[1023];
}

__global__ void scatter_kernel(const int* __restrict__ src, const int* __restrict__ dst,
                               const int* __restrict__ offs, int* __restrict__ cursor,
                               int* __restrict__ csr_src, int* __restrict__ csr_dst, int E) {
  int e = blockIdx.x * blockDim.x + threadIdx.x;
  if (e >= E) return;
  int d = dst[e];
  int pos = offs[d] + atomicAdd(&cursor[d], 1);
  csr_src[pos] = src[e];
  csr_dst[pos] = d;
}

// ---------------- edge-parallel logits (adaptive lanes/edge) ---------------
// q bf16 at qkvs[.,0:d], k bf16 at qkvs[.,d:2d]; row stride 4d.
// lpe = 1<<lpe_log2 lanes per edge (16 for d>=128, 8 for d=64, 4 for d=32).
__global__ __launch_bounds__(256) void edge_logit_kernel(
    const __bf16* __restrict__ qkvs, const int* __restrict__ csr_src,
    const int* __restrict__ csr_dst, float* __restrict__ logits,
    int E, int d, float scale, int lpe_log2) {
  const int t = blockIdx.x * 256 + threadIdx.x;
  const int g = t >> lpe_log2;
  const int lpe = 1 << lpe_log2;
  const int l = t & (lpe - 1);
  if (g >= E) return;
  const int ld = 4 * d;
  const int s = csr_src[g];
  const int dt = csr_dst[g];
  const __bf16* qr = qkvs + (size_t)dt * ld;
  const __bf16* kr = qkvs + (size_t)s * ld + d;
  const int n8 = d >> 3;
  float p = 0.f;
  for (int i = l; i < n8; i += lpe) {
    bf16x8 qv = *(const bf16x8*)(qr + i * 8);
    bf16x8 kv = *(const bf16x8*)(kr + i * 8);
#pragma unroll
    for (int j = 0; j < 8; ++j) p += (float)qv[j] * (float)kv[j];
  }
  for (int off = lpe >> 1; off; off >>= 1) p += __shfl_xor(p, off);
  if (l == 0) logits[g] = p * scale;
}

// ---------------- per-node softmax + aggregate (grouped gathers) -----------
// Wave covers FS = lpg*8 features (seg selects slice). ng = 64/lpg groups per
// wave; group g processes edges begin+g, begin+g+ng, ... independently (no
// shuffles in the loop; logit/src loads broadcast within group; 16B v loads).
// Butterfly over group bits combines partials. v at qkvs[.,2d:3d], skip at
// qkvs[.,3d:4d]. Writes h bf16 [N][d] = elu(agg + skip).
__global__ __launch_bounds__(256) void attn_agg_kernel(
    const __bf16* __restrict__ qkvs, const int* __restrict__ csr_src,
    const int* __restrict__ offs, const float* __restrict__ logits,
    __bf16* __restrict__ h_out, int N, int d, int segs_log2, int lpg_log2) {
  const int W = (blockIdx.x * 256 + threadIdx.x) >> 6;
  const int lane = threadIdx.x & 63;
  const int node = W >> segs_log2;
  const int seg = W & ((1 << segs_log2) - 1);
  if (node >= N) return;
  const int lpg = 1 << lpg_log2;
  const int ng = 64 >> lpg_log2;
  const int g = lane >> lpg_log2;
  const int l = lane & (lpg - 1);
  const int f0 = seg * (lpg << 3) + l * 8;  // 8 feats per lane
  const int ld = 4 * d;
  const int begin = offs[node];
  const int deg = offs[node + 1] - begin;

  // node max over logits (all 64 lanes)
  float m = -INFINITY;
  for (int i = lane; i < deg; i += 64) m = fmaxf(m, logits[begin + i]);
#pragma unroll
  for (int off = 32; off; off >>= 1) m = fmaxf(m, __shfl_xor(m, off));

  float acc[8] = {0.f, 0.f, 0.f, 0.f, 0.f, 0.f, 0.f, 0.f};
  float ssum = 0.f;
  const __bf16* vbase = qkvs + 2 * (size_t)d;

  for (int i = g; i < deg; i += ng) {
    int pos = begin + i;
    float w = __expf(logits[pos] - m);
    int s = csr_src[pos];
    ssum += w;
    bf16x8 vv = *(const bf16x8*)(vbase + (size_t)s * ld + f0);
#pragma unroll
    for (int j = 0; j < 8; ++j) acc[j] += w * (float)vv[j];
  }

  // combine groups (same l, different g)
  for (int off = lpg; off < 64; off <<= 1) {
    ssum += __shfl_xor(ssum, off);
#pragma unroll
    for (int j = 0; j < 8; ++j) acc[j] += __shfl_xor(acc[j], off);
  }
  float inv = (deg > 0) ? (1.0f / ssum) : 0.f;

  bf16x8 sk = *(const bf16x8*)(qkvs + (size_t)node * ld + 3 * d + f0);
  bf16x8 o;
#pragma unroll
  for (int j = 0; j < 8; ++j) {
    float r = acc[j] * inv + (float)sk[j];
    r = (r > 0.f) ? r : expm1f(r);
    o[j] = (__bf16)r;
  }
  *(bf16x8*)(h_out + (size_t)node * d + f0) = o;
}

// ---------------- pooling (atomic-free, h in bf16) ----------------
__global__ void gate_kernel(const __bf16* __restrict__ h, const float* __restrict__ Wg,
                            const float* __restrict__ bg, float* __restrict__ gate, int N) {
  int n = blockIdx.x * blockDim.x + threadIdx.x;
  if (n >= N) return;
  const bf16x8* hn = (const bf16x8*)(h + (size_t)n * 32);
  float g = bg[0];
#pragma unroll
  for (int i = 0; i < 4; ++i) {
    bf16x8 a = hn[i];
#pragma unroll
    for (int j = 0; j < 8; ++j) g += (float)a[j] * Wg[i * 8 + j];
  }
  gate[n] = g;
}

__global__ void bounds_kernel(const int* __restrict__ batch, int* __restrict__ bounds,
                              int N, int G) {
  int g = threadIdx.x;
  if (g > G) return;
  int lo = 0, hi = N;
  while (lo < hi) {
    int mid = (lo + hi) >> 1;
    if (batch[mid] < g) lo = mid + 1;
    else hi = mid;
  }
  bounds[g] = lo;
}

__global__ __launch_bounds__(256) void pool_final_kernel(
    const __bf16* __restrict__ h, const float* __restrict__ gate,
    const int* __restrict__ bounds, const float* __restrict__ Wf,
    const float* __restrict__ bf_, float* __restrict__ out) {
  __shared__ float red[256];
  __shared__ float pooled_s[32];
  __shared__ float m_s, inv_s;
  const int g = blockIdx.x;
  const int tid = threadIdx.x;
  const int s = bounds[g];
  const int e_end = bounds[g + 1];

  float m = -INFINITY;
  for (int i = s + tid; i < e_end; i += 256) m = fmaxf(m, gate[i]);
  red[tid] = m;
  __syncthreads();
  for (int off = 128; off; off >>= 1) {
    if (tid < off) red[tid] = fmaxf(red[tid], red[tid + off]);
    __syncthreads();
  }
  if (tid == 0) m_s = red[0];
  __syncthreads();
  m = m_s;

  float ss = 0.f;
  for (int i = s + tid; i < e_end; i += 256) ss += __expf(gate[i] - m);
  red[tid] = ss;
  __syncthreads();
  for (int off = 128; off; off >>= 1) {
    if (tid < off) red[tid] += red[tid + off];
    __syncthreads();
  }
  if (tid == 0) inv_s = (e_end > s) ? (1.0f / red[0]) : 0.f;
  __syncthreads();
  const float inv = inv_s;

  const int f = tid & 31;
  const int grp = tid >> 5;
  float acc = 0.f;
  for (int i = s + grp; i < e_end; i += 8)
    acc += __expf(gate[i] - m) * (float)h[(size_t)i * 32 + f];
  red[tid] = acc;
  __syncthreads();
  if (tid < 32) {
    float a = 0.f;
#pragma unroll
    for (int j = 0; j < 8; ++j) a += red[j * 32 + tid];
    pooled_s[tid] = a * inv;
  }
  __syncthreads();

  if (tid < 9) {
    float o = bf_[tid];
#pragma unroll
    for (int kk = 0; kk < 32; ++kk) o += pooled_s[kk] * Wf[kk * 9 + tid];
    out[g * 9 + tid] = o;
  }
}

// ---------------------------------------------------------------------------
extern "C" void kernel_launch(void* const* d_in, const int* in_sizes, int n_in,
                              void* d_out, int out_size, void* d_ws, size_t ws_size,
                              hipStream_t stream) {
  const int N = in_sizes[2];       // 10000 nodes
  const int E = in_sizes[1] / 2;   // 160000 edges
  const int G = 16;

  const float* x = (const float*)d_in[0];
  const int* ei = (const int*)d_in[1];
  const int* batch = (const int*)d_in[2];
  const int* src = ei;
  const int* dst = ei + E;
  const float* Wg = (const float*)d_in[35];
  const float* bg = (const float*)d_in[36];
  const float* Wf = (const float*)d_in[37];
  const float* bf_ = (const float*)d_in[38];
  float* out = (float*)d_out;

  char* p = (char*)d_ws;
  auto carve = [&](size_t bytes) -> char* {
    char* r = p;
    p += (bytes + 255) & ~(size_t)255;
    return r;
  };
  int* deg = (int*)carve((size_t)N * 4);
  int* offs = (int*)carve((size_t)(N + 1) * 4);
  int* cursor = (int*)carve((size_t)N * 4);
  int* csr_src = (int*)carve((size_t)E * 4);
  int* csr_dst = (int*)carve((size_t)E * 4);
  float* logits = (float*)carve((size_t)E * 4);
  __bf16* Ab = (__bf16*)carve((size_t)N * 128 * 2);
  __bf16* Wt = (__bf16*)carve((size_t)860160 * 2);
  float* bcat = (float*)carve(3456 * 4);
  __bf16* qkvs = (__bf16*)carve((size_t)N * 2048 * 2);
  __bf16* ha = (__bf16*)carve((size_t)N * 512 * 2);
  __bf16* hb = (__bf16*)carve((size_t)N * 512 * 2);
  float* gate = (float*)carve((size_t)N * 4);
  int* bounds = (int*)carve((size_t)(G + 1) * 4);
  (void)ws_size;

  // ---- CSR build ----
  hipMemsetAsync(deg, 0, (size_t)N * 4, stream);
  hipMemsetAsync(cursor, 0, (size_t)N * 4, stream);
  hist_kernel<<<(E + 255) / 256, 256, 0, stream>>>(dst, deg, E);
  scan_kernel<<<1, 1024, 0, stream>>>(deg, offs, N);
  scatter_kernel<<<(E + 255) / 256, 256, 0, stream>>>(src, dst, offs, cursor, csr_src, csr_dst, E);

  cast_bf16_kernel<<<(N * 128 / 4 + 255) / 256, 256, 0, stream>>>(x, Ab, N * 128 / 4);
  const float** di = (const float**)d_in;
  pack_all_kernel<<<(860160 + 3456 + 255) / 256, 256, 0, stream>>>(
      di[3], di[5], di[7], di[9], di[4], di[6], di[8], di[10],
      di[11], di[13], di[15], di[17], di[12], di[14], di[16], di[18],
      di[19], di[21], di[23], di[25], di[20], di[22], di[24], di[26],
      di[27], di[29], di[31], di[33], di[28], di[30], di[32], di[34],
      Wt, bcat);

  // ---- layers ----
  const int fins[4] = {128, 512, 256, 64};
  const int fouts[4] = {512, 256, 64, 32};
  const size_t woffs[4] = {0, 262144, 786432, 851968};
  const int boffs[4] = {0, 2048, 3072, 3328};
  const __bf16* hin = Ab;
  __bf16* houts[4] = {ha, hb, ha, hb};

  for (int l = 0; l < 4; ++l) {
    const int fin = fins[l], fout = fouts[l];
    const int Nc = 4 * fout;
    __bf16* hout = houts[l];

    dim3 grid(Nc / GBN, (N + GBM - 1) / GBM);
    gemm_mfma_kernel<<<grid, 256, 0, stream>>>(hin, Wt + woffs[l], bcat + boffs[l],
                                               qkvs, N, fin, Nc);

    float scale = 1.0f / sqrtf((float)fout);
    // lanes/edge: 16 for d>=128, else d/8
    int lpe_log2 = (fout >= 128) ? 4 : (fout == 64 ? 3 : 2);
    size_t lthreads = (size_t)E << lpe_log2;
    edge_logit_kernel<<<(lthreads + 255) / 256, 256, 0, stream>>>(
        qkvs, csr_src, csr_dst, logits, E, fout, scale, lpe_log2);

    // groups: lpg = min(16, d/8); segs = d / (lpg*8)
    int lpg_log2 = (fout >= 128) ? 4 : (fout == 64 ? 3 : 2);
    int fs = 8 << lpg_log2;
    int segs_log2 = 0;
    while ((fs << segs_log2) < fout) ++segs_log2;
    size_t waves = (size_t)N << segs_log2;
    attn_agg_kernel<<<(waves * 64 + 255) / 256, 256, 0, stream>>>(
        qkvs, csr_src, offs, logits, hout, N, fout, segs_log2, lpg_log2);
    hin = hout;
  }

  // ---- pooling ----
  gate_kernel<<<(N + 255) / 256, 256, 0, stream>>>(hin, Wg, bg, gate, N);
  bounds_kernel<<<1, G + 1, 0, stream>>>(batch, bounds, N, G);
  pool_final_kernel<<<G, 256, 0, stream>>>(hin, gate, bounds, Wf, bf_, out);
}

// Round 8
// 369.128 us; speedup vs baseline: 4.7064x; 1.0397x over previous
//
#include <hip/hip_runtime.h>
#include <hip/hip_bf16.h>
#include <math.h>

// ---------------------------------------------------------------------------
// TransformerNet: 4x TransformerConv (heads=1) + ELU, GlobalAttention pool,
// final linear.
// R1: edge-parallel logits + per-node softmax-agg.
// R2: atomic-free pooling (sorted batch -> binary-search bounds).
// R3: fused q|k|v|s bf16 MFMA GEMM per layer.   R4: k/v/h bf16.
// R5: GEMM LDS fixes + all-bf16 qkvs.           R6: grouped attn gathers.
// R7: GEMM staging via global_load_lds width=16 (async DMA, XOR-swizzled
//     unpadded LDS tile: lane loads seg s^(row&7), reads un-swizzle ->
//     conflict-free at structural minimum); gate fused into layer-4 attn;
//     bounds folded into pool_final; deg+cursor single memset.
// ---------------------------------------------------------------------------

typedef __bf16 bf16x8 __attribute__((ext_vector_type(8)));
typedef __bf16 bf16x4 __attribute__((ext_vector_type(4)));
typedef float f32x4 __attribute__((ext_vector_type(4)));

#define GBM 128
#define GBN 128
#define GBK 64

#if __has_builtin(__builtin_amdgcn_global_load_lds)
#define ASYNC_LDS 1
__device__ __forceinline__ void gload16(const __bf16* g, __bf16* l) {
  __builtin_amdgcn_global_load_lds(
      (const __attribute__((address_space(1))) unsigned int*)g,
      (__attribute__((address_space(3))) unsigned int*)l, 16, 0, 0);
}
#endif

// Fused GEMM: A[M,K](bf16) @ Wt[Nc,K]^T + bias -> qkvs[M][Nc] (bf16)
// LDS tile 128x64 bf16, row stride 64 (128B). Physical seg p of row r holds
// logical seg p^(r&7).
__global__ __launch_bounds__(256) void gemm_mfma_kernel(
    const __bf16* __restrict__ A, const __bf16* __restrict__ Bt,
    const float* __restrict__ bias, __bf16* __restrict__ qkvs,
    int M, int K, int Nc) {
  __shared__ __bf16 As[GBM * 64];
  __shared__ __bf16 Bs[GBN * 64];
  const int tid = threadIdx.x;
  const int wave = tid >> 6;
  const int lane = tid & 63;
  const int quad = lane >> 4;
  const int l16 = lane & 15;
  const int m0 = blockIdx.y * GBM;
  const int n0 = blockIdx.x * GBN;
  const int wm = (wave & 1) * 64;
  const int wn = (wave >> 1) * 64;

  const int r8 = lane >> 3;   // row within 8-row group
  const int sseg = lane & 7;  // physical 16B segment this lane fills

  f32x4 acc[4][4] = {};

  for (int k0 = 0; k0 < K; k0 += GBK) {
#pragma unroll
    for (int it = 0; it < 4; ++it) {
      const int rbase = wave * 32 + it * 8;  // wave-uniform
      const int row = rbase + r8;
      const int sw = sseg ^ r8;  // XOR-swizzled source segment (row&7 == r8)
      const __bf16* ga = A + (size_t)(m0 + row) * K + k0 + sw * 8;
      const __bf16* gb = Bt + (size_t)(n0 + row) * K + k0 + sw * 8;
#ifdef ASYNC_LDS
      gload16(ga, As + rbase * 64);  // HW: lane i -> base + i*16B
      gload16(gb, Bs + rbase * 64);
#else
      *(bf16x8*)(As + row * 64 + sseg * 8) = *(const bf16x8*)ga;
      *(bf16x8*)(Bs + row * 64 + sseg * 8) = *(const bf16x8*)gb;
#endif
    }
    __syncthreads();

#pragma unroll
    for (int ks = 0; ks < 2; ++ks) {
      bf16x8 af[4], bfr[4];
#pragma unroll
      for (int i = 0; i < 4; ++i) {
        const int ra = wm + i * 16 + l16;
        const int rb = wn + i * 16 + l16;
        const int ps = ((ks * 4 + quad) ^ (l16 & 7)) * 8;  // un-swizzle
        af[i]  = *(const bf16x8*)(As + ra * 64 + ps);
        bfr[i] = *(const bf16x8*)(Bs + rb * 64 + ps);
      }
#pragma unroll
      for (int mi = 0; mi < 4; ++mi)
#pragma unroll
        for (int ni = 0; ni < 4; ++ni)
          acc[mi][ni] = __builtin_amdgcn_mfma_f32_16x16x32_bf16(
              af[mi], bfr[ni], acc[mi][ni], 0, 0, 0);
    }
    __syncthreads();
  }

  float bsv[4];
#pragma unroll
  for (int ni = 0; ni < 4; ++ni) bsv[ni] = bias[n0 + wn + ni * 16 + l16];
#pragma unroll
  for (int mi = 0; mi < 4; ++mi) {
#pragma unroll
    for (int r = 0; r < 4; ++r) {
      int row = m0 + wm + mi * 16 + quad * 4 + r;
      if (row < M) {
        size_t rb = (size_t)row * Nc;
#pragma unroll
        for (int ni = 0; ni < 4; ++ni) {
          int col = n0 + wn + ni * 16 + l16;
          qkvs[rb + col] = (__bf16)(acc[mi][ni][r] + bsv[ni]);
        }
      }
    }
  }
}

// ---- pack ALL layers' weights -> transposed bf16 + concat fp32 biases ----
__global__ void pack_all_kernel(
    const float* W0q, const float* W0k, const float* W0v, const float* W0s,
    const float* b0q, const float* b0k, const float* b0v, const float* b0s,
    const float* W1q, const float* W1k, const float* W1v, const float* W1s,
    const float* b1q, const float* b1k, const float* b1v, const float* b1s,
    const float* W2q, const float* W2k, const float* W2v, const float* W2s,
    const float* b2q, const float* b2k, const float* b2v, const float* b2s,
    const float* W3q, const float* W3k, const float* W3v, const float* W3s,
    const float* b3q, const float* b3k, const float* b3v, const float* b3s,
    __bf16* __restrict__ Wt, float* __restrict__ bcat) {
  const int t = blockIdx.x * 256 + threadIdx.x;
  if (t < 860160) {
    int l, local, ksh, fsh;
    if (t < 262144)      { l = 0; local = t;          ksh = 7; fsh = 9; }
    else if (t < 786432) { l = 1; local = t - 262144; ksh = 9; fsh = 8; }
    else if (t < 851968) { l = 2; local = t - 786432; ksh = 8; fsh = 6; }
    else                 { l = 3; local = t - 851968; ksh = 6; fsh = 5; }
    const int K = 1 << ksh, fout = 1 << fsh;
    int c = local >> ksh;
    int kk = local & (K - 1);
    int blk = c >> fsh;
    int j = c & (fout - 1);
    const float* W;
    if (l == 0)      W = blk == 0 ? W0q : blk == 1 ? W0k : blk == 2 ? W0v : W0s;
    else if (l == 1) W = blk == 0 ? W1q : blk == 1 ? W1k : blk == 2 ? W1v : W1s;
    else if (l == 2) W = blk == 0 ? W2q : blk == 1 ? W2k : blk == 2 ? W2v : W2s;
    else             W = blk == 0 ? W3q : blk == 1 ? W3k : blk == 2 ? W3v : W3s;
    Wt[t] = (__bf16)W[((size_t)kk << fsh) + j];
  } else if (t < 860160 + 3456) {
    int u = t - 860160;
    int l, local, fsh, boff;
    if (u < 2048)      { l = 0; local = u;        fsh = 9; boff = 0; }
    else if (u < 3072) { l = 1; local = u - 2048; fsh = 8; boff = 2048; }
    else if (u < 3328) { l = 2; local = u - 3072; fsh = 6; boff = 3072; }
    else               { l = 3; local = u - 3328; fsh = 5; boff = 3328; }
    const int fout = 1 << fsh;
    int blk = local >> fsh, j = local & (fout - 1);
    const float* b;
    if (l == 0)      b = blk == 0 ? b0q : blk == 1 ? b0k : blk == 2 ? b0v : b0s;
    else if (l == 1) b = blk == 0 ? b1q : blk == 1 ? b1k : blk == 2 ? b1v : b1s;
    else if (l == 2) b = blk == 0 ? b2q : blk == 1 ? b2k : blk == 2 ? b2v : b2s;
    else             b = blk == 0 ? b3q : blk == 1 ? b3k : blk == 2 ? b3v : b3s;
    bcat[boff + local] = b[j];
  }
}

__global__ void cast_bf16_kernel(const float* __restrict__ in, __bf16* __restrict__ out,
                                 int n4) {
  int i = blockIdx.x * blockDim.x + threadIdx.x;
  if (i >= n4) return;
  float4 v = ((const float4*)in)[i];
  bf16x4 o;
  o[0] = (__bf16)v.x; o[1] = (__bf16)v.y; o[2] = (__bf16)v.z; o[3] = (__bf16)v.w;
  *(bf16x4*)(out + (size_t)i * 4) = o;
}

// ---------------- CSR build ----------------
__global__ void hist_kernel(const int* __restrict__ dst, int* __restrict__ deg, int E) {
  int e = blockIdx.x * blockDim.x + threadIdx.x;
  if (e < E) atomicAdd(&deg[dst[e]], 1);
}

__global__ __launch_bounds__(1024) void scan_kernel(const int* __restrict__ deg,
                                                    int* __restrict__ offs, int N) {
  __shared__ int sums[1024];
  const int tid = threadIdx.x;
  const int chunk = (N + 1023) / 1024;
  const int start = tid * chunk;
  int s = 0;
  for (int i = 0; i < chunk; ++i) {
    int idx = start + i;
    if (idx < N) s += deg[idx];
  }
  sums[tid] = s;
  __syncthreads();
  for (int off = 1; off < 1024; off <<= 1) {
    int t = (tid >= off) ? sums[tid - off] : 0;
    __syncthreads();
    sums[tid] += t;
    __syncthreads();
  }
  int run = (tid == 0) ? 0 : sums[tid - 1];
  for (int i = 0; i < chunk; ++i) {
    int idx = start + i;
    if (idx < N) {
      offs[idx] = run;
      run += deg[idx];
    }
  }
  if (tid == 1023) offs[N] = sums[1023];
}

__global__ void scatter_kernel(const int* __restrict__ src, const int* __restrict__ dst,
                               const int* __restrict__ offs, int* __restrict__ cursor,
                               int* __restrict__ csr_src, int* __restrict__ csr_dst, int E) {
  int e = blockIdx.x * blockDim.x + threadIdx.x;
  if (e >= E) return;
  int d = dst[e];
  int pos = offs[d] + atomicAdd(&cursor[d], 1);
  csr_src[pos] = src[e];
  csr_dst[pos] = d;
}

// ---------------- edge-parallel logits (adaptive lanes/edge) ---------------
__global__ __launch_bounds__(256) void edge_logit_kernel(
    const __bf16* __restrict__ qkvs, const int* __restrict__ csr_src,
    const int* __restrict__ csr_dst, float* __restrict__ logits,
    int E, int d, float scale, int lpe_log2) {
  const int t = blockIdx.x * 256 + threadIdx.x;
  const int g = t >> lpe_log2;
  const int lpe = 1 << lpe_log2;
  const int l = t & (lpe - 1);
  if (g >= E) return;
  const int ld = 4 * d;
  const int s = csr_src[g];
  const int dt = csr_dst[g];
  const __bf16* qr = qkvs + (size_t)dt * ld;
  const __bf16* kr = qkvs + (size_t)s * ld + d;
  const int n8 = d >> 3;
  float p = 0.f;
  for (int i = l; i < n8; i += lpe) {
    bf16x8 qv = *(const bf16x8*)(qr + i * 8);
    bf16x8 kv = *(const bf16x8*)(kr + i * 8);
#pragma unroll
    for (int j = 0; j < 8; ++j) p += (float)qv[j] * (float)kv[j];
  }
  for (int off = lpe >> 1; off; off >>= 1) p += __shfl_xor(p, off);
  if (l == 0) logits[g] = p * scale;
}

// ---------------- per-node softmax + aggregate (grouped gathers) -----------
// For the last layer, gate_out != nullptr: fuses gate = elu_h . Wg + bg.
__global__ __launch_bounds__(256) void attn_agg_kernel(
    const __bf16* __restrict__ qkvs, const int* __restrict__ csr_src,
    const int* __restrict__ offs, const float* __restrict__ logits,
    __bf16* __restrict__ h_out, int N, int d, int segs_log2, int lpg_log2,
    const float* __restrict__ Wg, const float* __restrict__ bg,
    float* __restrict__ gate_out) {
  const int W = (blockIdx.x * 256 + threadIdx.x) >> 6;
  const int lane = threadIdx.x & 63;
  const int node = W >> segs_log2;
  const int seg = W & ((1 << segs_log2) - 1);
  if (node >= N) return;
  const int lpg = 1 << lpg_log2;
  const int ng = 64 >> lpg_log2;
  const int g = lane >> lpg_log2;
  const int l = lane & (lpg - 1);
  const int f0 = seg * (lpg << 3) + l * 8;
  const int ld = 4 * d;
  const int begin = offs[node];
  const int deg = offs[node + 1] - begin;

  float m = -INFINITY;
  for (int i = lane; i < deg; i += 64) m = fmaxf(m, logits[begin + i]);
#pragma unroll
  for (int off = 32; off; off >>= 1) m = fmaxf(m, __shfl_xor(m, off));

  float acc[8] = {0.f, 0.f, 0.f, 0.f, 0.f, 0.f, 0.f, 0.f};
  float ssum = 0.f;
  const __bf16* vbase = qkvs + 2 * (size_t)d;

#pragma unroll 2
  for (int i = g; i < deg; i += ng) {
    int pos = begin + i;
    float w = __expf(logits[pos] - m);
    int s = csr_src[pos];
    ssum += w;
    bf16x8 vv = *(const bf16x8*)(vbase + (size_t)s * ld + f0);
#pragma unroll
    for (int j = 0; j < 8; ++j) acc[j] += w * (float)vv[j];
  }

  for (int off = lpg; off < 64; off <<= 1) {
    ssum += __shfl_xor(ssum, off);
#pragma unroll
    for (int j = 0; j < 8; ++j) acc[j] += __shfl_xor(acc[j], off);
  }
  float inv = (deg > 0) ? (1.0f / ssum) : 0.f;

  float rr[8];
  bf16x8 sk = *(const bf16x8*)(qkvs + (size_t)node * ld + 3 * d + f0);
  bf16x8 o;
#pragma unroll
  for (int j = 0; j < 8; ++j) {
    float r = acc[j] * inv + (float)sk[j];
    r = (r > 0.f) ? r : expm1f(r);
    rr[j] = r;
    o[j] = (__bf16)r;
  }
  *(bf16x8*)(h_out + (size_t)node * d + f0) = o;

  if (gate_out) {  // last layer: d == 32, segs == 1, all lanes active
    float gp = 0.f;
#pragma unroll
    for (int j = 0; j < 8; ++j) gp += rr[j] * Wg[f0 + j];
    for (int off = 1; off < lpg; off <<= 1) gp += __shfl_xor(gp, off);
    if (lane == 0) gate_out[node] = gp + bg[0];
  }
}

// ---------------- pooling (atomic-free, bounds inline) ----------------
__global__ __launch_bounds__(256) void pool_final_kernel(
    const __bf16* __restrict__ h, const float* __restrict__ gate,
    const int* __restrict__ batch, int N, const float* __restrict__ Wf,
    const float* __restrict__ bf_, float* __restrict__ out) {
  __shared__ float red[256];
  __shared__ float pooled_s[32];
  __shared__ float m_s, inv_s;
  __shared__ int sb[2];
  const int g = blockIdx.x;
  const int tid = threadIdx.x;

  if (tid < 2) {
    int target = g + tid;
    int lo = 0, hi = N;
    while (lo < hi) {
      int mid = (lo + hi) >> 1;
      if (batch[mid] < target) lo = mid + 1;
      else hi = mid;
    }
    sb[tid] = lo;
  }
  __syncthreads();
  const int s = sb[0];
  const int e_end = sb[1];

  float m = -INFINITY;
  for (int i = s + tid; i < e_end; i += 256) m = fmaxf(m, gate[i]);
  red[tid] = m;
  __syncthreads();
  for (int off = 128; off; off >>= 1) {
    if (tid < off) red[tid] = fmaxf(red[tid], red[tid + off]);
    __syncthreads();
  }
  if (tid == 0) m_s = red[0];
  __syncthreads();
  m = m_s;

  float ss = 0.f;
  for (int i = s + tid; i < e_end; i += 256) ss += __expf(gate[i] - m);
  red[tid] = ss;
  __syncthreads();
  for (int off = 128; off; off >>= 1) {
    if (tid < off) red[tid] += red[tid + off];
    __syncthreads();
  }
  if (tid == 0) inv_s = (e_end > s) ? (1.0f / red[0]) : 0.f;
  __syncthreads();
  const float inv = inv_s;

  const int f = tid & 31;
  const int grp = tid >> 5;
  float acc = 0.f;
  for (int i = s + grp; i < e_end; i += 8)
    acc += __expf(gate[i] - m) * (float)h[(size_t)i * 32 + f];
  red[tid] = acc;
  __syncthreads();
  if (tid < 32) {
    float a = 0.f;
#pragma unroll
    for (int j = 0; j < 8; ++j) a += red[j * 32 + tid];
    pooled_s[tid] = a * inv;
  }
  __syncthreads();

  if (tid < 9) {
    float o = bf_[tid];
#pragma unroll
    for (int kk = 0; kk < 32; ++kk) o += pooled_s[kk] * Wf[kk * 9 + tid];
    out[g * 9 + tid] = o;
  }
}

// ---------------------------------------------------------------------------
extern "C" void kernel_launch(void* const* d_in, const int* in_sizes, int n_in,
                              void* d_out, int out_size, void* d_ws, size_t ws_size,
                              hipStream_t stream) {
  const int N = in_sizes[2];       // 10000 nodes
  const int E = in_sizes[1] / 2;   // 160000 edges
  const int G = 16;
  const int NP = N + 128;          // padded rows for async-LDS OOB tile reads

  const float* x = (const float*)d_in[0];
  const int* ei = (const int*)d_in[1];
  const int* batch = (const int*)d_in[2];
  const int* src = ei;
  const int* dst = ei + E;
  const float* Wg = (const float*)d_in[35];
  const float* bg = (const float*)d_in[36];
  const float* Wf = (const float*)d_in[37];
  const float* bf_ = (const float*)d_in[38];
  float* out = (float*)d_out;

  char* p = (char*)d_ws;
  auto carve = [&](size_t bytes) -> char* {
    char* r = p;
    p += (bytes + 255) & ~(size_t)255;
    return r;
  };
  int* deg = (int*)carve((size_t)2 * N * 4);  // deg | cursor contiguous
  int* cursor = deg + N;
  int* offs = (int*)carve((size_t)(N + 1) * 4);
  int* csr_src = (int*)carve((size_t)E * 4);
  int* csr_dst = (int*)carve((size_t)E * 4);
  float* logits = (float*)carve((size_t)E * 4);
  __bf16* Ab = (__bf16*)carve((size_t)NP * 128 * 2);
  __bf16* Wt = (__bf16*)carve((size_t)860160 * 2);
  float* bcat = (float*)carve(3456 * 4);
  __bf16* qkvs = (__bf16*)carve((size_t)N * 2048 * 2);
  __bf16* ha = (__bf16*)carve((size_t)NP * 512 * 2);
  __bf16* hb = (__bf16*)carve((size_t)NP * 512 * 2);
  float* gate = (float*)carve((size_t)N * 4);
  (void)ws_size;

  // ---- CSR build ----
  hipMemsetAsync(deg, 0, (size_t)2 * N * 4, stream);
  hist_kernel<<<(E + 255) / 256, 256, 0, stream>>>(dst, deg, E);
  scan_kernel<<<1, 1024, 0, stream>>>(deg, offs, N);
  scatter_kernel<<<(E + 255) / 256, 256, 0, stream>>>(src, dst, offs, cursor, csr_src, csr_dst, E);

  cast_bf16_kernel<<<(N * 128 / 4 + 255) / 256, 256, 0, stream>>>(x, Ab, N * 128 / 4);
  const float** di = (const float**)d_in;
  pack_all_kernel<<<(860160 + 3456 + 255) / 256, 256, 0, stream>>>(
      di[3], di[5], di[7], di[9], di[4], di[6], di[8], di[10],
      di[11], di[13], di[15], di[17], di[12], di[14], di[16], di[18],
      di[19], di[21], di[23], di[25], di[20], di[22], di[24], di[26],
      di[27], di[29], di[31], di[33], di[28], di[30], di[32], di[34],
      Wt, bcat);

  // ---- layers ----
  const int fins[4] = {128, 512, 256, 64};
  const int fouts[4] = {512, 256, 64, 32};
  const size_t woffs[4] = {0, 262144, 786432, 851968};
  const int boffs[4] = {0, 2048, 3072, 3328};
  const __bf16* hin = Ab;
  __bf16* houts[4] = {ha, hb, ha, hb};

  for (int l = 0; l < 4; ++l) {
    const int fin = fins[l], fout = fouts[l];
    const int Nc = 4 * fout;
    __bf16* hout = houts[l];

    dim3 grid(Nc / GBN, (N + GBM - 1) / GBM);
    gemm_mfma_kernel<<<grid, 256, 0, stream>>>(hin, Wt + woffs[l], bcat + boffs[l],
                                               qkvs, N, fin, Nc);

    float scale = 1.0f / sqrtf((float)fout);
    int lpe_log2 = (fout >= 128) ? 4 : (fout == 64 ? 3 : 2);
    size_t lthreads = (size_t)E << lpe_log2;
    edge_logit_kernel<<<(lthreads + 255) / 256, 256, 0, stream>>>(
        qkvs, csr_src, csr_dst, logits, E, fout, scale, lpe_log2);

    int lpg_log2 = (fout >= 128) ? 4 : (fout == 64 ? 3 : 2);
    int fs = 8 << lpg_log2;
    int segs_log2 = 0;
    while ((fs << segs_log2) < fout) ++segs_log2;
    size_t waves = (size_t)N << segs_log2;
    const bool last = (l == 3);
    attn_agg_kernel<<<(waves * 64 + 255) / 256, 256, 0, stream>>>(
        qkvs, csr_src, offs, logits, hout, N, fout, segs_log2, lpg_log2,
        last ? Wg : nullptr, last ? bg : nullptr, last ? gate : nullptr);
    hin = hout;
  }

  // ---- pooling ----
  pool_final_kernel<<<G, 256, 0, stream>>>(hin, gate, batch, N, Wf, bf_, out);
}